// Round 22
// baseline (125.542 us; speedup 1.0000x reference)
//
#include <hip/hip_runtime.h>
#include <math.h>

// Model_6150393168181 — bf16-MFMA pipeline.
// Launches: prep_all (+SS zero) -> prep_mb -> chainL1..L4 -> cl4b -> sage -> attn.
// Math: out[b] = f @ Z / sqrt(128), Z = sum_w MB_w^T (f^T SB_w^T);
//   MB_w[e][d] = sum_o' ksa[w,o',e] qsa[w,o',d];  f = rms(relu(SAGE4(rms(flows))));
//   SAGE agg (rows 0..127): corr_l = L @ (s.X_l @ wl_l^T), L[n][i]=(i<n)/max(n,1).
// v7: sage_k split from prep_mb -> 33KB LDS, 4 blocks/CU (was 2 at 65KB).
// All streamed MFMA fragments (WRp, SBp, MBT) in wave-coalesced order [tile][ks][lane][8].

typedef __attribute__((ext_vector_type(8))) short bf16x8;
typedef __attribute__((ext_vector_type(4))) float f32x4;

__device__ inline ushort f2b(float x) {
  unsigned u = __builtin_bit_cast(unsigned, x);
  unsigned r = (u + 0x7fffu + ((u >> 16) & 1u)) >> 16;
  return (ushort)r;
}
__device__ inline int ftswz(int e) { return ((e & 7) ^ ((e >> 3) & 15)) << 4; }

// ---------------- prep: SBp (permuted) + WL/WR (row-major) + WRp (permuted) + SS zero ----------------
__global__ __launch_bounds__(256) void prep_all_k(
    const float* __restrict__ s2w,
    const float* __restrict__ wl1, const float* __restrict__ wl2,
    const float* __restrict__ wl3, const float* __restrict__ wl4,
    const float* __restrict__ wr1, const float* __restrict__ wr2,
    const float* __restrict__ wr3, const float* __restrict__ wr4,
    ushort* __restrict__ SBp, ushort* __restrict__ WL, ushort* __restrict__ WR,
    ushort* __restrict__ WRp, float* __restrict__ SS) {
  if (blockIdx.x == 0) {
    SS[threadIdx.x] = 0.f;
    SS[threadIdx.x + 256] = 0.f;
  }
  int i = blockIdx.x * 256 + threadIdx.x;
  if (i < 131072) {
    int w = i >> 14, p = (i >> 7) & 127, m = i & 127;
    int sidx = ((((w * 2 + (p >> 6)) * 4 + ((p >> 4) & 3)) * 4 + (m >> 5)) * 64 +
                ((m >> 3) & 3) * 16 + (p & 15)) * 8 + (m & 7);
    SBp[sidx] = f2b(s2w[p * 1024 + m * 8 + w]);
    return;
  }
  i -= 131072;
  if (i < 98304) {
    float v, u;
    int base, K, col, k;
    if (i < 16384)      { v = wl1[i];         u = wr1[i];         base = 0;     K = 128; col = i >> 7;            k = i & 127; }
    else if (i < 49152) { int j = i - 16384;  v = wl2[j]; u = wr2[j]; base = 16384; K = 128; col = j >> 7;       k = j & 127; }
    else if (i < 81920) { int j = i - 49152;  v = wl3[j]; u = wr3[j]; base = 49152; K = 256; col = j >> 8;       k = j & 255; }
    else                { int j = i - 81920;  v = wl4[j]; u = wr4[j]; base = 81920; K = 128; col = j >> 7;       k = j & 127; }
    WL[i] = f2b(v);
    ushort ub = f2b(u);
    WR[i] = ub;
    int pidx = base + (((col >> 4) * (K / 32) + (k >> 5)) * 64 +
                       ((k >> 3) & 3) * 16 + (col & 15)) * 8 + (k & 7);
    WRp[pidx] = ub;
  }
}

// ---------------- prep_mb: MBT permuted (own kernel, 64K LDS) ----------------
__global__ __launch_bounds__(256, 1) void prep_mb_k(
    const float* __restrict__ qsa, const float* __restrict__ ksa,
    ushort* __restrict__ MBT) {
  __shared__ char QT[32768];
  __shared__ char KTm[32768];
  const int tid = threadIdx.x;
  const int lane = tid & 63, wv = tid >> 6, lr = lane & 15, lg = lane >> 4;
  int w = blockIdx.x;
  const float* qw = qsa + (size_t)w * 16384;
  const float* kw = ksa + (size_t)w * 16384;
  for (int e = tid; e < 16384; e += 256) {
    int op = e >> 7, c = e & 127;
    int off = c * 256 + ((op * 2) ^ ((c & 7) << 4));
    *reinterpret_cast<ushort*>(QT + off)  = f2b(qw[e]);
    *reinterpret_cast<ushort*>(KTm + off) = f2b(kw[e]);
  }
  __syncthreads();
  #pragma unroll
  for (int rt = 0; rt < 2; ++rt) {
    int e = wv * 32 + rt * 16 + lr;
    bf16x8 a[4];
    #pragma unroll
    for (int ks = 0; ks < 4; ++ks)
      a[ks] = *reinterpret_cast<const bf16x8*>(KTm + e * 256 + ((ks * 64 + lg * 16) ^ ((e & 7) << 4)));
    #pragma unroll
    for (int ct = 0; ct < 8; ++ct) {
      int d = ct * 16 + lr;
      bf16x8 bq[4];
      #pragma unroll
      for (int ks = 0; ks < 4; ++ks)
        bq[ks] = *reinterpret_cast<const bf16x8*>(QT + d * 256 + ((ks * 64 + lg * 16) ^ ((d & 7) << 4)));
      f32x4 acc = {0.f, 0.f, 0.f, 0.f};
      #pragma unroll
      for (int ks = 0; ks < 4; ++ks)
        acc = __builtin_amdgcn_mfma_f32_16x16x32_bf16(a[ks], bq[ks], acc, 0, 0, 0);
      uint2 pk;
      pk.x = (unsigned)f2b(acc[0]) | ((unsigned)f2b(acc[1]) << 16);
      pk.y = (unsigned)f2b(acc[2]) | ((unsigned)f2b(acc[3]) << 16);
      size_t base = ((((size_t)ct * 8 + w) * 4 + wv) * 64 +
                     (size_t)(((rt * 2 + (lg >> 1)) & 3) * 16 + lr)) * 8 + (lg & 1) * 4;
      *reinterpret_cast<uint2*>(&MBT[base]) = pk;
    }
  }
}

// ---------------- chain layer kernel (WL/WR row-major) ----------------
template <int K, int N, int MODE>
__global__ __launch_bounds__(256, 1) void chainL_k(
    const float* __restrict__ flows, const ushort* __restrict__ XTsrc,
    const float* __restrict__ SSprev,
    const ushort* __restrict__ Wl, const ushort* __restrict__ Wr,
    const float* __restrict__ bias,
    ushort* __restrict__ XTdst, float* __restrict__ YTdst, float* __restrict__ SScur) {
  __shared__ char XS[K * 272];
  __shared__ char C0T[4096];
  __shared__ float sArr[128];

  const int tid = threadIdx.x;
  const int lane = tid & 63, wv = tid >> 6, lr = lane & 15, lg = lane >> 4;
  const int cG0 = blockIdx.x * 16;

  if (MODE == 0) {
    #pragma unroll
    for (int it = 0; it < 16; ++it) {
      int idx = tid + it * 256;
      int row = idx >> 5, c4 = idx & 31;
      const float4 v = *reinterpret_cast<const float4*>(flows + (size_t)row * 128 + c4 * 4);
      float ss = v.x * v.x + v.y * v.y + v.z * v.z + v.w * v.w;
      ss += __shfl_xor(ss, 16); ss += __shfl_xor(ss, 8);
      ss += __shfl_xor(ss, 4);  ss += __shfl_xor(ss, 2); ss += __shfl_xor(ss, 1);
      *reinterpret_cast<ushort*>(XS + (c4 * 4 + 0) * 272 + row * 2) = f2b(v.x);
      *reinterpret_cast<ushort*>(XS + (c4 * 4 + 1) * 272 + row * 2) = f2b(v.y);
      *reinterpret_cast<ushort*>(XS + (c4 * 4 + 2) * 272 + row * 2) = f2b(v.z);
      *reinterpret_cast<ushort*>(XS + (c4 * 4 + 3) * 272 + row * 2) = f2b(v.w);
      if ((tid & 31) == 0) sArr[row] = rsqrtf(ss * (1.0f / 128.0f));
    }
  } else {
    for (int e = tid * 8; e < K * 128; e += 2048) {
      uint4 v = *reinterpret_cast<const uint4*>(XTsrc + e);
      *reinterpret_cast<uint4*>(XS + (e >> 7) * 272 + (e & 127) * 2) = v;
    }
    if (tid < 128) sArr[tid] = 1.0f / fmaxf(sqrtf(SSprev[tid]), 1e-12f);
  }
  __syncthreads();

  bf16x8 a[2][K / 32];
  float sr[2][4];
  #pragma unroll
  for (int mt = 0; mt < 2; ++mt) {
    int R = wv * 32 + mt * 16 + lr;
    #pragma unroll
    for (int ks = 0; ks < K / 32; ++ks) {
      union { ushort us[8]; bf16x8 v; } u;
      #pragma unroll
      for (int j = 0; j < 8; ++j)
        u.us[j] = *reinterpret_cast<const ushort*>(XS + (ks * 32 + lg * 8 + j) * 272 + R * 2);
      a[mt][ks] = u.v;
    }
    #pragma unroll
    for (int rr = 0; rr < 4; ++rr) sr[mt][rr] = sArr[wv * 32 + mt * 16 + 4 * lg + rr];
  }

  bf16x8 aL[2][4];
  #pragma unroll
  for (int mt = 0; mt < 2; ++mt) {
    int rowL = wv * 32 + mt * 16 + lr;
    ushort iv = f2b(1.0f / (float)(rowL > 1 ? rowL : 1));
    #pragma unroll
    for (int ks = 0; ks < 4; ++ks)
      #pragma unroll
      for (int j = 0; j < 8; ++j) {
        int k = ks * 32 + lg * 8 + j;
        aL[mt][ks][j] = (short)((k < rowL) ? iv : 0);
      }
  }

  const int cG = cG0 + lr;
  {
    bf16x8 bw[K / 32];
    #pragma unroll
    for (int ks = 0; ks < K / 32; ++ks)
      bw[ks] = *reinterpret_cast<const bf16x8*>(Wl + (size_t)cG * K + ks * 32 + lg * 8);
    #pragma unroll
    for (int mt = 0; mt < 2; ++mt) {
      f32x4 acc = {0.f, 0.f, 0.f, 0.f};
      #pragma unroll
      for (int ks = 0; ks < K / 32; ++ks)
        acc = __builtin_amdgcn_mfma_f32_16x16x32_bf16(a[mt][ks], bw[ks], acc, 0, 0, 0);
      int m0 = wv * 32 + mt * 16 + lg * 4;
      uint2 pk;
      pk.x = (unsigned)f2b(acc[0] * sr[mt][0]) | ((unsigned)f2b(acc[1] * sr[mt][1]) << 16);
      pk.y = (unsigned)f2b(acc[2] * sr[mt][2]) | ((unsigned)f2b(acc[3] * sr[mt][3]) << 16);
      *reinterpret_cast<uint2*>(C0T + lr * 256 + ((2 * m0) ^ ((lr & 7) << 4))) = pk;
    }
  }
  __syncthreads();

  {
    bf16x8 bc[4], bw[K / 32];
    #pragma unroll
    for (int ks = 0; ks < 4; ++ks)
      bc[ks] = *reinterpret_cast<const bf16x8*>(C0T + lr * 256 + ((ks * 64 + lg * 16) ^ ((lr & 7) << 4)));
    #pragma unroll
    for (int ks = 0; ks < K / 32; ++ks)
      bw[ks] = *reinterpret_cast<const bf16x8*>(Wr + (size_t)cG * K + ks * 32 + lg * 8);
    float bb = bias[cG];
    #pragma unroll
    for (int mt = 0; mt < 2; ++mt) {
      f32x4 cacc = {0.f, 0.f, 0.f, 0.f}, acc = {0.f, 0.f, 0.f, 0.f};
      #pragma unroll
      for (int ks = 0; ks < 4; ++ks)
        cacc = __builtin_amdgcn_mfma_f32_16x16x32_bf16(aL[mt][ks], bc[ks], cacc, 0, 0, 0);
      #pragma unroll
      for (int ks = 0; ks < K / 32; ++ks)
        acc = __builtin_amdgcn_mfma_f32_16x16x32_bf16(a[mt][ks], bw[ks], acc, 0, 0, 0);
      int m0 = wv * 32 + mt * 16 + lg * 4;
      float ssq[4];
      if (MODE < 2) {
        float y0 = acc[0] * sr[mt][0] + bb + cacc[0];
        float y1 = acc[1] * sr[mt][1] + bb + cacc[1];
        float y2 = acc[2] * sr[mt][2] + bb + cacc[2];
        float y3 = acc[3] * sr[mt][3] + bb + cacc[3];
        uint2 pk;
        pk.x = (unsigned)f2b(y0) | ((unsigned)f2b(y1) << 16);
        pk.y = (unsigned)f2b(y2) | ((unsigned)f2b(y3) << 16);
        *reinterpret_cast<uint2*>(&XTdst[(size_t)cG * 128 + m0]) = pk;
        ssq[0] = y0 * y0; ssq[1] = y1 * y1; ssq[2] = y2 * y2; ssq[3] = y3 * y3;
      } else {
        float4 vv;
        vv.x = fmaxf(acc[0] * sr[mt][0] + bb + cacc[0], 0.f);
        vv.y = fmaxf(acc[1] * sr[mt][1] + bb + cacc[1], 0.f);
        vv.z = fmaxf(acc[2] * sr[mt][2] + bb + cacc[2], 0.f);
        vv.w = fmaxf(acc[3] * sr[mt][3] + bb + cacc[3], 0.f);
        *reinterpret_cast<float4*>(&YTdst[(size_t)cG * 128 + m0]) = vv;
        ssq[0] = vv.x * vv.x; ssq[1] = vv.y * vv.y; ssq[2] = vv.z * vv.z; ssq[3] = vv.w * vv.w;
      }
      #pragma unroll
      for (int rr = 0; rr < 4; ++rr) {
        float ss = ssq[rr];
        ss += __shfl_xor(ss, 1); ss += __shfl_xor(ss, 2);
        ss += __shfl_xor(ss, 4); ss += __shfl_xor(ss, 8);
        if (lr == 0) atomicAdd(&SScur[m0 + rr], ss);
      }
    }
  }
}

// ---------------- cl4b ----------------
__global__ __launch_bounds__(256) void cl4b_k(
    const float* __restrict__ YT, const float* __restrict__ SS4,
    ushort* __restrict__ Fg) {
  int t = blockIdx.x * 256 + threadIdx.x;
  int r = t >> 4, cs = t & 15;
  float sc = sqrtf(128.0f / fmaxf(SS4[r], 1e-20f));
  ushort tmp[8];
  #pragma unroll
  for (int j = 0; j < 8; ++j) {
    int c = cs * 8 + j;
    tmp[j] = f2b(YT[(size_t)c * 128 + r] * sc);
  }
  *reinterpret_cast<uint4*>(&Fg[(size_t)r * 128 + cs * 8]) = *reinterpret_cast<uint4*>(tmp);
}

// ---------------- sage helpers ----------------
__device__ inline void stage_flows64(const float* __restrict__ flows, int blk,
                                     char* Xt, float* sArr, int wv, int lane) {
  int r2 = lane >> 5;
  int c4 = lane & 31;
  #pragma unroll
  for (int it = 0; it < 8; ++it) {
    int rowbase = wv * 16 + it * 2;
    const float4 v = *reinterpret_cast<const float4*>(
        flows + ((size_t)blk * 64 + rowbase) * 128 + lane * 4);
    int row = rowbase + r2;
    float ss = v.x * v.x + v.y * v.y + v.z * v.z + v.w * v.w;
    ss += __shfl_xor(ss, 16); ss += __shfl_xor(ss, 8);
    ss += __shfl_xor(ss, 4);  ss += __shfl_xor(ss, 2); ss += __shfl_xor(ss, 1);
    uint2 pk;
    pk.x = (unsigned)f2b(v.x) | ((unsigned)f2b(v.y) << 16);
    pk.y = (unsigned)f2b(v.z) | ((unsigned)f2b(v.w) << 16);
    *reinterpret_cast<uint2*>(Xt + row * 256 + ((c4 * 8) ^ ((row & 7) << 4))) = pk;
    if (c4 == 0) sArr[row] = rsqrtf(ss * (1.0f / 128.0f));
  }
}

template <int K, int N>
__device__ inline void sage_layer_mid64(char* Xt, const float* sP, float* sN,
                                        const ushort* __restrict__ Wrp,
                                        const float* __restrict__ bias,
                                        int wv, int lr, int lg, int l64) {
  __syncthreads();
  bf16x8 a[K / 32];
  float sr[4];
  int rowA = wv * 16 + lr;
  #pragma unroll
  for (int ks = 0; ks < K / 32; ++ks)
    a[ks] = *reinterpret_cast<const bf16x8*>(
        Xt + rowA * (K * 2) + ((ks * 64 + lg * 16) ^ ((rowA & 7) << 4)));
  #pragma unroll
  for (int rr = 0; rr < 4; ++rr) sr[rr] = sP[wv * 16 + 4 * lg + rr];
  __syncthreads();
  float ssq[4] = {0.f, 0.f, 0.f, 0.f};
  #pragma unroll
  for (int nt = 0; nt < N / 16; ++nt) {
    int col = nt * 16 + lr;
    bf16x8 b[K / 32];
    #pragma unroll
    for (int ks = 0; ks < K / 32; ++ks)
      b[ks] = *reinterpret_cast<const bf16x8*>(Wrp + (((size_t)nt * (K / 32) + ks) * 64 + l64) * 8);
    f32x4 acc = {0.f, 0.f, 0.f, 0.f};
    #pragma unroll
    for (int ks = 0; ks < K / 32; ++ks)
      acc = __builtin_amdgcn_mfma_f32_16x16x32_bf16(a[ks], b[ks], acc, 0, 0, 0);
    float bb = bias[col];
    #pragma unroll
    for (int rr = 0; rr < 4; ++rr) {
      int row = wv * 16 + 4 * lg + rr;
      float y = acc[rr] * sr[rr] + bb;
      *reinterpret_cast<ushort*>(Xt + row * (N * 2) + ((col * 2) ^ ((row & 7) << 4))) = f2b(y);
      ssq[rr] += y * y;
    }
  }
  #pragma unroll
  for (int rr = 0; rr < 4; ++rr) {
    float ss = ssq[rr];
    ss += __shfl_xor(ss, 1); ss += __shfl_xor(ss, 2);
    ss += __shfl_xor(ss, 4); ss += __shfl_xor(ss, 8);
    if (lr == 0) sN[wv * 16 + 4 * lg + rr] = 1.0f / fmaxf(sqrtf(ss), 1e-12f);
  }
}

__device__ inline void sage_layer_last64(char* Xt, const float* sP,
                                         const ushort* __restrict__ Wrp,
                                         const float* __restrict__ bias,
                                         int wv, int lr, int lg, int l64,
                                         ushort* __restrict__ Fg, int blk) {
  __syncthreads();
  bf16x8 a[4];
  float sr[4];
  int rowA = wv * 16 + lr;
  #pragma unroll
  for (int ks = 0; ks < 4; ++ks)
    a[ks] = *reinterpret_cast<const bf16x8*>(
        Xt + rowA * 256 + ((ks * 64 + lg * 16) ^ ((rowA & 7) << 4)));
  #pragma unroll
  for (int rr = 0; rr < 4; ++rr) sr[rr] = sP[wv * 16 + 4 * lg + rr];
  __syncthreads();
  float yreg[8][4];
  float ssq[4] = {0.f, 0.f, 0.f, 0.f};
  #pragma unroll
  for (int nt = 0; nt < 8; ++nt) {
    int col = nt * 16 + lr;
    bf16x8 b[4];
    #pragma unroll
    for (int ks = 0; ks < 4; ++ks)
      b[ks] = *reinterpret_cast<const bf16x8*>(Wrp + (((size_t)nt * 4 + ks) * 64 + l64) * 8);
    f32x4 acc = {0.f, 0.f, 0.f, 0.f};
    #pragma unroll
    for (int ks = 0; ks < 4; ++ks)
      acc = __builtin_amdgcn_mfma_f32_16x16x32_bf16(a[ks], b[ks], acc, 0, 0, 0);
    float bb = bias[col];
    #pragma unroll
    for (int rr = 0; rr < 4; ++rr) {
      float y = acc[rr] * sr[rr] + bb;
      yreg[nt][rr] = y;
      float v = fmaxf(y, 0.f);
      ssq[rr] += v * v;
    }
  }
  float sc[4];
  #pragma unroll
  for (int rr = 0; rr < 4; ++rr) {
    float ss = ssq[rr];
    ss += __shfl_xor(ss, 1); ss += __shfl_xor(ss, 2);
    ss += __shfl_xor(ss, 4); ss += __shfl_xor(ss, 8);
    sc[rr] = sqrtf(128.0f / fmaxf(ss, 1e-20f));
  }
  #pragma unroll
  for (int nt = 0; nt < 8; ++nt)
    #pragma unroll
    for (int rr = 0; rr < 4; ++rr) {
      int row = wv * 16 + 4 * lg + rr;
      Fg[((size_t)blk * 64 + row) * 128 + nt * 16 + lr] = f2b(fmaxf(yreg[nt][rr], 0.f) * sc[rr]);
    }
}

// ---------------- sage kernel: 510 blocks, 33KB LDS -> 4 blocks/CU ----------------
__global__ __launch_bounds__(256, 4) void sage_k(
    const float* __restrict__ flows,
    const ushort* __restrict__ WRp,
    const float* __restrict__ bl1, const float* __restrict__ bl2,
    const float* __restrict__ bl3, const float* __restrict__ bl4,
    ushort* __restrict__ Fg) {
  __shared__ char Xt[32768];
  __shared__ float sA[64], sB[64];
  const int tid = threadIdx.x;
  const int lane = tid & 63, wv = tid >> 6, lr = lane & 15, lg = lane >> 4;
  const int l64 = lane;
  int blk = blockIdx.x + 2;
  stage_flows64(flows, blk, Xt, sA, wv, lane);
  sage_layer_mid64<128, 128>(Xt, sA, sB, WRp + 0,     bl1, wv, lr, lg, l64);
  sage_layer_mid64<128, 256>(Xt, sB, sA, WRp + 16384, bl2, wv, lr, lg, l64);
  sage_layer_mid64<256, 128>(Xt, sA, sB, WRp + 49152, bl3, wv, lr, lg, l64);
  sage_layer_last64(Xt, sB, WRp + 81920, bl4, wv, lr, lg, l64, Fg, blk);
}

// ---------------- attn v6: 512 blocks x 512 thr, dbuf RT, coalesced SBp/MBT ----------------
__global__ __launch_bounds__(512, 4) void attn_fused(
    const ushort* __restrict__ F, const ushort* __restrict__ MBT,
    const ushort* __restrict__ SBp, float* __restrict__ Out) {
  __shared__ char FT[32768];
  __shared__ char RTb[32768];

  const int bq = blockIdx.x;
  const int b = bq >> 1, ph = bq & 1;
  const int tid = threadIdx.x;
  const int l = tid & 63, wv = tid >> 6;
  const int lr = l & 15, lg = l >> 4;

  const ushort* Fb = F + (size_t)b * 16384;

  #pragma unroll
  for (int it = 0; it < 4; ++it) {
    int idx = tid + it * 512;
    int m = idx >> 4, eg = idx & 15;
    uint4 v = *reinterpret_cast<const uint4*>(Fb + m * 128 + eg * 8);
    const ushort* pv = reinterpret_cast<const ushort*>(&v);
    #pragma unroll
    for (int j = 0; j < 8; ++j) {
      int e = eg * 8 + j;
      *reinterpret_cast<ushort*>(FT + e * 256 + ((m * 2) ^ ftswz(e))) = pv[j];
    }
  }

  bf16x8 fa[4];
  {
    int n = wv * 16 + lr;
    #pragma unroll
    for (int ks = 0; ks < 4; ++ks)
      fa[ks] = *reinterpret_cast<const bf16x8*>(Fb + n * 128 + ks * 32 + lg * 8);
  }
  __syncthreads();

  bf16x8 af[4];
  {
    int e = wv * 16 + lr;
    #pragma unroll
    for (int ks = 0; ks < 4; ++ks)
      af[ks] = *reinterpret_cast<const bf16x8*>(
          FT + e * 256 + ((ks * 64 + lg * 16) ^ ftswz(e)));
  }

  f32x4 zacc[4];
  #pragma unroll
  for (int pt = 0; pt < 4; ++pt) zacc[pt] = f32x4{0.f, 0.f, 0.f, 0.f};

  const int eb0 = 2 * (wv * 16 + lg * 4);

  auto Rphase = [&](int w, char* RT) {
    #pragma unroll
    for (int pt = 0; pt < 4; ++pt) {
      int p = pt * 16 + lr;
      bf16x8 bs[4];
      #pragma unroll
      for (int ks = 0; ks < 4; ++ks)
        bs[ks] = *reinterpret_cast<const bf16x8*>(
            SBp + ((((size_t)(w * 2 + ph) * 4 + pt) * 4 + ks) * 64 + l) * 8);
      f32x4 rr = {0.f, 0.f, 0.f, 0.f};
      #pragma unroll
      for (int ks = 0; ks < 4; ++ks)
        rr = __builtin_amdgcn_mfma_f32_16x16x32_bf16(af[ks], bs[ks], rr, 0, 0, 0);
      uint2 pk;
      pk.x = (unsigned)f2b(rr[0]) | ((unsigned)f2b(rr[1]) << 16);
      pk.y = (unsigned)f2b(rr[2]) | ((unsigned)f2b(rr[3]) << 16);
      *reinterpret_cast<uint2*>(RT + p * 256 + (eb0 ^ ((p & 7) << 4))) = pk;
    }
  };
  auto Zphase = [&](int w, const char* RT) {
    bf16x8 mf[4];
    #pragma unroll
    for (int ks = 0; ks < 4; ++ks)
      mf[ks] = *reinterpret_cast<const bf16x8*>(
          MBT + ((((size_t)wv * 8 + w) * 4 + ks) * 64 + l) * 8);
    #pragma unroll
    for (int pt = 0; pt < 4; ++pt) {
      int p = pt * 16 + lr;
      bf16x8 bg[4];
      #pragma unroll
      for (int ks = 0; ks < 4; ++ks)
        bg[ks] = *reinterpret_cast<const bf16x8*>(
            RT + p * 256 + ((ks * 64 + lg * 16) ^ ((p & 7) << 4)));
      #pragma unroll
      for (int ks = 0; ks < 4; ++ks)
        zacc[pt] = __builtin_amdgcn_mfma_f32_16x16x32_bf16(mf[ks], bg[ks], zacc[pt], 0, 0, 0);
    }
  };

  Rphase(0, RTb);
  __syncthreads();
  #pragma unroll
  for (int w = 0; w < 7; ++w) {
    Zphase(w, RTb + (w & 1) * 16384);
    Rphase(w + 1, RTb + ((w + 1) & 1) * 16384);
    __syncthreads();
  }
  Zphase(7, RTb + 16384);
  #pragma unroll
  for (int pt = 0; pt < 4; ++pt) {
    int p = pt * 16 + lr;
    uint2 pk;
    pk.x = (unsigned)f2b(zacc[pt][0]) | ((unsigned)f2b(zacc[pt][1]) << 16);
    pk.y = (unsigned)f2b(zacc[pt][2]) | ((unsigned)f2b(zacc[pt][3]) << 16);
    *reinterpret_cast<uint2*>(RTb + p * 256 + (eb0 ^ ((p & 7) << 4))) = pk;
  }
  __syncthreads();

  const float inv_scale = 0.08838834764831845f;
  float* ob = Out + (size_t)b * 16384 + ph * 64;
  #pragma unroll
  for (int pt = 0; pt < 4; ++pt) {
    int p = pt * 16 + lr;
    bf16x8 bz[4];
    #pragma unroll
    for (int ks = 0; ks < 4; ++ks)
      bz[ks] = *reinterpret_cast<const bf16x8*>(
          RTb + p * 256 + ((ks * 64 + lg * 16) ^ ((p & 7) << 4)));
    f32x4 oa = {0.f, 0.f, 0.f, 0.f};
    #pragma unroll
    for (int ks = 0; ks < 4; ++ks)
      oa = __builtin_amdgcn_mfma_f32_16x16x32_bf16(fa[ks], bz[ks], oa, 0, 0, 0);
    int n0 = wv * 16 + lg * 4;
    #pragma unroll
    for (int r = 0; r < 4; ++r)
      ob[(size_t)(n0 + r) * 128 + p] = oa[r] * inv_scale;
  }
}

extern "C" void kernel_launch(void* const* d_in, const int* in_sizes, int n_in,
                              void* d_out, int out_size, void* d_ws, size_t ws_size,
                              hipStream_t stream) {
  const float* flows = (const float*)d_in[0];
  const float* g1_wl = (const float*)d_in[10];
  const float* g1_bl = (const float*)d_in[11];
  const float* g1_wr = (const float*)d_in[12];
  const float* g2_wl = (const float*)d_in[13];
  const float* g2_bl = (const float*)d_in[14];
  const float* g2_wr = (const float*)d_in[15];
  const float* g3_wl = (const float*)d_in[16];
  const float* g3_bl = (const float*)d_in[17];
  const float* g3_wr = (const float*)d_in[18];
  const float* g4_wl = (const float*)d_in[19];
  const float* g4_bl = (const float*)d_in[20];
  const float* g4_wr = (const float*)d_in[21];
  const float* qsa   = (const float*)d_in[24];
  const float* ksa   = (const float*)d_in[25];
  const float* s2w   = (const float*)d_in[27];
  float* out = (float*)d_out;
  char* wsb  = (char*)d_ws;

  // workspace layout (bytes)
  ushort* FB16 = (ushort*)(wsb);                 // 32768*128 bf16 = 8388608
  ushort* SBp  = (ushort*)(wsb + 8388608);       // 131072 bf16 (permuted)
  ushort* WL   = (ushort*)(wsb + 8650752);       // 98304 bf16
  ushort* WR   = (ushort*)(wsb + 8847360);       // 98304 bf16
  ushort* MBT  = (ushort*)(wsb + 9043968);       // 131072 bf16 (permuted)
  ushort* XT1  = (ushort*)(wsb + 9306112);       // 128*128 bf16
  ushort* XT2  = (ushort*)(wsb + 9338880);       // 256*128 bf16
  ushort* XT3  = (ushort*)(wsb + 9404416);       // 128*128 bf16
  float*  YT4  = (float*)(wsb + 9437184);        // 128*128 f32
  float*  SS   = (float*)(wsb + 9502720);        // 4*128 f32
  ushort* WRp  = (ushort*)(wsb + 9504768);       // 98304 bf16 (permuted)

  prep_all_k<<<896, 256, 0, stream>>>(s2w,
                                      g1_wl, g2_wl, g3_wl, g4_wl,
                                      g1_wr, g2_wr, g3_wr, g4_wr,
                                      SBp, WL, WR, WRp, SS);
  prep_mb_k<<<8, 256, 0, stream>>>(qsa, ksa, MBT);
  chainL_k<128, 128, 0><<<8, 256, 0, stream>>>(flows, nullptr, nullptr,
                                               WL + 0, WR + 0, g1_bl, XT1, nullptr, SS + 0);
  chainL_k<128, 256, 1><<<16, 256, 0, stream>>>(nullptr, XT1, SS + 0,
                                                WL + 16384, WR + 16384, g2_bl, XT2, nullptr, SS + 128);
  chainL_k<256, 128, 1><<<8, 256, 0, stream>>>(nullptr, XT2, SS + 128,
                                               WL + 49152, WR + 49152, g3_bl, XT3, nullptr, SS + 256);
  chainL_k<128, 128, 2><<<8, 256, 0, stream>>>(nullptr, XT3, SS + 256,
                                               WL + 81920, WR + 81920, g4_bl, nullptr, YT4, SS + 384);
  cl4b_k<<<8, 256, 0, stream>>>(YT4, SS + 384, FB16);
  sage_k<<<510, 256, 0, stream>>>(flows, WRp, g1_bl, g2_bl, g3_bl, g4_bl, FB16);
  attn_fused<<<512, 512, 0, stream>>>(FB16, MBT, SBp, out);
}

// Round 24
// 118.105 us; speedup vs baseline: 1.0630x; 1.0630x over previous
//
#include <hip/hip_runtime.h>
#include <math.h>

// Model_6150393168181 — bf16-MFMA pipeline.
// Launches: prep_all (+SS zero) -> chainL1..L4 -> cl4b -> mega (sage+prep_mb) -> attn.
// Math: out[b] = f @ Z / sqrt(128), Z = sum_w MB_w^T (f^T SB_w^T);
//   MB_w[e][d] = sum_o' ksa[w,o',e] qsa[w,o',d];  f = rms(relu(SAGE4(rms(flows))));
//   SAGE agg (rows 0..127): corr_l = L @ (s.X_l @ wl_l^T), L[n][i]=(i<n)/max(n,1).
// v9: sage path is barrier-free (all LDS rows wave-private, disjoint A->B->C->A buffers)
// with asm volatile("" ::: "memory") compiler fences between layers (round-23 failure was
// TBAA-permitted reordering of next-layer ds_reads above current-layer ds_writes, NOT a
// hardware race; same-wave DS ops execute in order).
// All streamed MFMA fragments (WRp, SBp, MBT) in wave-coalesced order [tile][ks][lane][8].

typedef __attribute__((ext_vector_type(8))) short bf16x8;
typedef __attribute__((ext_vector_type(4))) float f32x4;

__device__ inline ushort f2b(float x) {
  unsigned u = __builtin_bit_cast(unsigned, x);
  unsigned r = (u + 0x7fffu + ((u >> 16) & 1u)) >> 16;
  return (ushort)r;
}
__device__ inline int ftswz(int e) { return ((e & 7) ^ ((e >> 3) & 15)) << 4; }

// ---------------- prep: SBp (permuted) + WL/WR (row-major) + WRp (permuted) + SS zero ----------------
__global__ __launch_bounds__(256) void prep_all_k(
    const float* __restrict__ s2w,
    const float* __restrict__ wl1, const float* __restrict__ wl2,
    const float* __restrict__ wl3, const float* __restrict__ wl4,
    const float* __restrict__ wr1, const float* __restrict__ wr2,
    const float* __restrict__ wr3, const float* __restrict__ wr4,
    ushort* __restrict__ SBp, ushort* __restrict__ WL, ushort* __restrict__ WR,
    ushort* __restrict__ WRp, float* __restrict__ SS) {
  if (blockIdx.x == 0) {
    SS[threadIdx.x] = 0.f;
    SS[threadIdx.x + 256] = 0.f;
  }
  int i = blockIdx.x * 256 + threadIdx.x;
  if (i < 131072) {
    int w = i >> 14, p = (i >> 7) & 127, m = i & 127;
    int sidx = ((((w * 2 + (p >> 6)) * 4 + ((p >> 4) & 3)) * 4 + (m >> 5)) * 64 +
                ((m >> 3) & 3) * 16 + (p & 15)) * 8 + (m & 7);
    SBp[sidx] = f2b(s2w[p * 1024 + m * 8 + w]);
    return;
  }
  i -= 131072;
  if (i < 98304) {
    float v, u;
    int base, K, col, k;
    if (i < 16384)      { v = wl1[i];         u = wr1[i];         base = 0;     K = 128; col = i >> 7;            k = i & 127; }
    else if (i < 49152) { int j = i - 16384;  v = wl2[j]; u = wr2[j]; base = 16384; K = 128; col = j >> 7;       k = j & 127; }
    else if (i < 81920) { int j = i - 49152;  v = wl3[j]; u = wr3[j]; base = 49152; K = 256; col = j >> 8;       k = j & 255; }
    else                { int j = i - 81920;  v = wl4[j]; u = wr4[j]; base = 81920; K = 128; col = j >> 7;       k = j & 127; }
    WL[i] = f2b(v);
    ushort ub = f2b(u);
    WR[i] = ub;
    int pidx = base + (((col >> 4) * (K / 32) + (k >> 5)) * 64 +
                       ((k >> 3) & 3) * 16 + (col & 15)) * 8 + (k & 7);
    WRp[pidx] = ub;
  }
}

// ---------------- chain layer kernel (WL/WR row-major) ----------------
template <int K, int N, int MODE>
__global__ __launch_bounds__(256, 1) void chainL_k(
    const float* __restrict__ flows, const ushort* __restrict__ XTsrc,
    const float* __restrict__ SSprev,
    const ushort* __restrict__ Wl, const ushort* __restrict__ Wr,
    const float* __restrict__ bias,
    ushort* __restrict__ XTdst, float* __restrict__ YTdst, float* __restrict__ SScur) {
  __shared__ char XS[K * 272];
  __shared__ char C0T[4096];
  __shared__ float sArr[128];

  const int tid = threadIdx.x;
  const int lane = tid & 63, wv = tid >> 6, lr = lane & 15, lg = lane >> 4;
  const int cG0 = blockIdx.x * 16;

  if (MODE == 0) {
    #pragma unroll
    for (int it = 0; it < 16; ++it) {
      int idx = tid + it * 256;
      int row = idx >> 5, c4 = idx & 31;
      const float4 v = *reinterpret_cast<const float4*>(flows + (size_t)row * 128 + c4 * 4);
      float ss = v.x * v.x + v.y * v.y + v.z * v.z + v.w * v.w;
      ss += __shfl_xor(ss, 16); ss += __shfl_xor(ss, 8);
      ss += __shfl_xor(ss, 4);  ss += __shfl_xor(ss, 2); ss += __shfl_xor(ss, 1);
      *reinterpret_cast<ushort*>(XS + (c4 * 4 + 0) * 272 + row * 2) = f2b(v.x);
      *reinterpret_cast<ushort*>(XS + (c4 * 4 + 1) * 272 + row * 2) = f2b(v.y);
      *reinterpret_cast<ushort*>(XS + (c4 * 4 + 2) * 272 + row * 2) = f2b(v.z);
      *reinterpret_cast<ushort*>(XS + (c4 * 4 + 3) * 272 + row * 2) = f2b(v.w);
      if ((tid & 31) == 0) sArr[row] = rsqrtf(ss * (1.0f / 128.0f));
    }
  } else {
    for (int e = tid * 8; e < K * 128; e += 2048) {
      uint4 v = *reinterpret_cast<const uint4*>(XTsrc + e);
      *reinterpret_cast<uint4*>(XS + (e >> 7) * 272 + (e & 127) * 2) = v;
    }
    if (tid < 128) sArr[tid] = 1.0f / fmaxf(sqrtf(SSprev[tid]), 1e-12f);
  }
  __syncthreads();

  bf16x8 a[2][K / 32];
  float sr[2][4];
  #pragma unroll
  for (int mt = 0; mt < 2; ++mt) {
    int R = wv * 32 + mt * 16 + lr;
    #pragma unroll
    for (int ks = 0; ks < K / 32; ++ks) {
      union { ushort us[8]; bf16x8 v; } u;
      #pragma unroll
      for (int j = 0; j < 8; ++j)
        u.us[j] = *reinterpret_cast<const ushort*>(XS + (ks * 32 + lg * 8 + j) * 272 + R * 2);
      a[mt][ks] = u.v;
    }
    #pragma unroll
    for (int rr = 0; rr < 4; ++rr) sr[mt][rr] = sArr[wv * 32 + mt * 16 + 4 * lg + rr];
  }

  bf16x8 aL[2][4];
  #pragma unroll
  for (int mt = 0; mt < 2; ++mt) {
    int rowL = wv * 32 + mt * 16 + lr;
    ushort iv = f2b(1.0f / (float)(rowL > 1 ? rowL : 1));
    #pragma unroll
    for (int ks = 0; ks < 4; ++ks)
      #pragma unroll
      for (int j = 0; j < 8; ++j) {
        int k = ks * 32 + lg * 8 + j;
        aL[mt][ks][j] = (short)((k < rowL) ? iv : 0);
      }
  }

  const int cG = cG0 + lr;
  {
    bf16x8 bw[K / 32];
    #pragma unroll
    for (int ks = 0; ks < K / 32; ++ks)
      bw[ks] = *reinterpret_cast<const bf16x8*>(Wl + (size_t)cG * K + ks * 32 + lg * 8);
    #pragma unroll
    for (int mt = 0; mt < 2; ++mt) {
      f32x4 acc = {0.f, 0.f, 0.f, 0.f};
      #pragma unroll
      for (int ks = 0; ks < K / 32; ++ks)
        acc = __builtin_amdgcn_mfma_f32_16x16x32_bf16(a[mt][ks], bw[ks], acc, 0, 0, 0);
      int m0 = wv * 32 + mt * 16 + lg * 4;
      uint2 pk;
      pk.x = (unsigned)f2b(acc[0] * sr[mt][0]) | ((unsigned)f2b(acc[1] * sr[mt][1]) << 16);
      pk.y = (unsigned)f2b(acc[2] * sr[mt][2]) | ((unsigned)f2b(acc[3] * sr[mt][3]) << 16);
      *reinterpret_cast<uint2*>(C0T + lr * 256 + ((2 * m0) ^ ((lr & 7) << 4))) = pk;
    }
  }
  __syncthreads();

  {
    bf16x8 bc[4], bw[K / 32];
    #pragma unroll
    for (int ks = 0; ks < 4; ++ks)
      bc[ks] = *reinterpret_cast<const bf16x8*>(C0T + lr * 256 + ((ks * 64 + lg * 16) ^ ((lr & 7) << 4)));
    #pragma unroll
    for (int ks = 0; ks < K / 32; ++ks)
      bw[ks] = *reinterpret_cast<const bf16x8*>(Wr + (size_t)cG * K + ks * 32 + lg * 8);
    float bb = bias[cG];
    #pragma unroll
    for (int mt = 0; mt < 2; ++mt) {
      f32x4 cacc = {0.f, 0.f, 0.f, 0.f}, acc = {0.f, 0.f, 0.f, 0.f};
      #pragma unroll
      for (int ks = 0; ks < 4; ++ks)
        cacc = __builtin_amdgcn_mfma_f32_16x16x32_bf16(aL[mt][ks], bc[ks], cacc, 0, 0, 0);
      #pragma unroll
      for (int ks = 0; ks < K / 32; ++ks)
        acc = __builtin_amdgcn_mfma_f32_16x16x32_bf16(a[mt][ks], bw[ks], acc, 0, 0, 0);
      int m0 = wv * 32 + mt * 16 + lg * 4;
      float ssq[4];
      if (MODE < 2) {
        float y0 = acc[0] * sr[mt][0] + bb + cacc[0];
        float y1 = acc[1] * sr[mt][1] + bb + cacc[1];
        float y2 = acc[2] * sr[mt][2] + bb + cacc[2];
        float y3 = acc[3] * sr[mt][3] + bb + cacc[3];
        uint2 pk;
        pk.x = (unsigned)f2b(y0) | ((unsigned)f2b(y1) << 16);
        pk.y = (unsigned)f2b(y2) | ((unsigned)f2b(y3) << 16);
        *reinterpret_cast<uint2*>(&XTdst[(size_t)cG * 128 + m0]) = pk;
        ssq[0] = y0 * y0; ssq[1] = y1 * y1; ssq[2] = y2 * y2; ssq[3] = y3 * y3;
      } else {
        float4 vv;
        vv.x = fmaxf(acc[0] * sr[mt][0] + bb + cacc[0], 0.f);
        vv.y = fmaxf(acc[1] * sr[mt][1] + bb + cacc[1], 0.f);
        vv.z = fmaxf(acc[2] * sr[mt][2] + bb + cacc[2], 0.f);
        vv.w = fmaxf(acc[3] * sr[mt][3] + bb + cacc[3], 0.f);
        *reinterpret_cast<float4*>(&YTdst[(size_t)cG * 128 + m0]) = vv;
        ssq[0] = vv.x * vv.x; ssq[1] = vv.y * vv.y; ssq[2] = vv.z * vv.z; ssq[3] = vv.w * vv.w;
      }
      #pragma unroll
      for (int rr = 0; rr < 4; ++rr) {
        float ss = ssq[rr];
        ss += __shfl_xor(ss, 1); ss += __shfl_xor(ss, 2);
        ss += __shfl_xor(ss, 4); ss += __shfl_xor(ss, 8);
        if (lr == 0) atomicAdd(&SScur[m0 + rr], ss);
      }
    }
  }
}

// ---------------- cl4b ----------------
__global__ __launch_bounds__(256) void cl4b_k(
    const float* __restrict__ YT, const float* __restrict__ SS4,
    ushort* __restrict__ Fg) {
  int t = blockIdx.x * 256 + threadIdx.x;
  int r = t >> 4, cs = t & 15;
  float sc = sqrtf(128.0f / fmaxf(SS4[r], 1e-20f));
  ushort tmp[8];
  #pragma unroll
  for (int j = 0; j < 8; ++j) {
    int c = cs * 8 + j;
    tmp[j] = f2b(YT[(size_t)c * 128 + r] * sc);
  }
  *reinterpret_cast<uint4*>(&Fg[(size_t)r * 128 + cs * 8]) = *reinterpret_cast<uint4*>(tmp);
}

// ---------------- sage helpers (barrier-free, wave-private rows) ----------------
__device__ inline void stage_flows_nb(const float* __restrict__ flows, int blk,
                                      char* A_, float* sArr, int wv, int lane) {
  int r2 = lane >> 5;
  int c4 = lane & 31;
  #pragma unroll
  for (int it = 0; it < 8; ++it) {
    int rowbase = wv * 16 + it * 2;
    const float4 v = *reinterpret_cast<const float4*>(
        flows + ((size_t)blk * 64 + rowbase) * 128 + lane * 4);
    int row = rowbase + r2;
    float ss = v.x * v.x + v.y * v.y + v.z * v.z + v.w * v.w;
    ss += __shfl_xor(ss, 16); ss += __shfl_xor(ss, 8);
    ss += __shfl_xor(ss, 4);  ss += __shfl_xor(ss, 2); ss += __shfl_xor(ss, 1);
    uint2 pk;
    pk.x = (unsigned)f2b(v.x) | ((unsigned)f2b(v.y) << 16);
    pk.y = (unsigned)f2b(v.z) | ((unsigned)f2b(v.w) << 16);
    *reinterpret_cast<uint2*>(A_ + row * 256 + ((c4 * 8) ^ ((row & 7) << 4))) = pk;
    if (c4 == 0) sArr[row] = rsqrtf(ss * (1.0f / 128.0f));
  }
}

template <int K, int N>
__device__ inline void sage_layer_nb(const char* Xsrc, char* Xdst,
                                     const float* sP, float* sN,
                                     const ushort* __restrict__ Wrp,
                                     const float* __restrict__ bias,
                                     int wv, int lr, int lg, int l64) {
  bf16x8 a[K / 32];
  float sr[4];
  int rowA = wv * 16 + lr;
  #pragma unroll
  for (int ks = 0; ks < K / 32; ++ks)
    a[ks] = *reinterpret_cast<const bf16x8*>(
        Xsrc + rowA * (K * 2) + ((ks * 64 + lg * 16) ^ ((rowA & 7) << 4)));
  #pragma unroll
  for (int rr = 0; rr < 4; ++rr) sr[rr] = sP[wv * 16 + 4 * lg + rr];
  float ssq[4] = {0.f, 0.f, 0.f, 0.f};
  #pragma unroll
  for (int nt = 0; nt < N / 16; ++nt) {
    int col = nt * 16 + lr;
    bf16x8 b[K / 32];
    #pragma unroll
    for (int ks = 0; ks < K / 32; ++ks)
      b[ks] = *reinterpret_cast<const bf16x8*>(Wrp + (((size_t)nt * (K / 32) + ks) * 64 + l64) * 8);
    f32x4 acc = {0.f, 0.f, 0.f, 0.f};
    #pragma unroll
    for (int ks = 0; ks < K / 32; ++ks)
      acc = __builtin_amdgcn_mfma_f32_16x16x32_bf16(a[ks], b[ks], acc, 0, 0, 0);
    float bb = bias[col];
    #pragma unroll
    for (int rr = 0; rr < 4; ++rr) {
      int row = wv * 16 + 4 * lg + rr;
      float y = acc[rr] * sr[rr] + bb;
      *reinterpret_cast<ushort*>(Xdst + row * (N * 2) + ((col * 2) ^ ((row & 7) << 4))) = f2b(y);
      ssq[rr] += y * y;
    }
  }
  #pragma unroll
  for (int rr = 0; rr < 4; ++rr) {
    float ss = ssq[rr];
    ss += __shfl_xor(ss, 1); ss += __shfl_xor(ss, 2);
    ss += __shfl_xor(ss, 4); ss += __shfl_xor(ss, 8);
    if (lr == 0) sN[wv * 16 + 4 * lg + rr] = 1.0f / fmaxf(sqrtf(ss), 1e-12f);
  }
}

__device__ inline void sage_layer_last_nb(const char* Xsrc, const float* sP,
                                          const ushort* __restrict__ Wrp,
                                          const float* __restrict__ bias,
                                          int wv, int lr, int lg, int l64,
                                          ushort* __restrict__ Fg, int blk) {
  bf16x8 a[4];
  float sr[4];
  int rowA = wv * 16 + lr;
  #pragma unroll
  for (int ks = 0; ks < 4; ++ks)
    a[ks] = *reinterpret_cast<const bf16x8*>(
        Xsrc + rowA * 256 + ((ks * 64 + lg * 16) ^ ((rowA & 7) << 4)));
  #pragma unroll
  for (int rr = 0; rr < 4; ++rr) sr[rr] = sP[wv * 16 + 4 * lg + rr];
  float yreg[8][4];
  float ssq[4] = {0.f, 0.f, 0.f, 0.f};
  #pragma unroll
  for (int nt = 0; nt < 8; ++nt) {
    int col = nt * 16 + lr;
    bf16x8 b[4];
    #pragma unroll
    for (int ks = 0; ks < 4; ++ks)
      b[ks] = *reinterpret_cast<const bf16x8*>(Wrp + (((size_t)nt * 4 + ks) * 64 + l64) * 8);
    f32x4 acc = {0.f, 0.f, 0.f, 0.f};
    #pragma unroll
    for (int ks = 0; ks < 4; ++ks)
      acc = __builtin_amdgcn_mfma_f32_16x16x32_bf16(a[ks], b[ks], acc, 0, 0, 0);
    float bb = bias[col];
    #pragma unroll
    for (int rr = 0; rr < 4; ++rr) {
      float y = acc[rr] * sr[rr] + bb;
      yreg[nt][rr] = y;
      float v = fmaxf(y, 0.f);
      ssq[rr] += v * v;
    }
  }
  float sc[4];
  #pragma unroll
  for (int rr = 0; rr < 4; ++rr) {
    float ss = ssq[rr];
    ss += __shfl_xor(ss, 1); ss += __shfl_xor(ss, 2);
    ss += __shfl_xor(ss, 4); ss += __shfl_xor(ss, 8);
    sc[rr] = sqrtf(128.0f / fmaxf(ss, 1e-20f));
  }
  #pragma unroll
  for (int nt = 0; nt < 8; ++nt)
    #pragma unroll
    for (int rr = 0; rr < 4; ++rr) {
      int row = wv * 16 + 4 * lg + rr;
      Fg[((size_t)blk * 64 + row) * 128 + nt * 16 + lr] = f2b(fmaxf(yreg[nt][rr], 0.f) * sc[rr]);
    }
}

// ---------------- mega kernel: sage (0..509, barrier-free) + prep_mb (510..517) ----------------
__global__ __launch_bounds__(256, 2) void mega_k(
    const float* __restrict__ flows,
    const float* __restrict__ qsa, const float* __restrict__ ksa,
    const ushort* __restrict__ WRp,
    const float* __restrict__ bl1, const float* __restrict__ bl2,
    const float* __restrict__ bl3, const float* __restrict__ bl4,
    ushort* __restrict__ Fg, ushort* __restrict__ MBT) {
  __shared__ char L[66560];
  const int bid = blockIdx.x;
  const int tid = threadIdx.x;
  const int lane = tid & 63, wv = tid >> 6, lr = lane & 15, lg = lane >> 4;
  const int l64 = lane;

  if (bid < 510) {
    char* A_ = L;                    // 16K (stage in, L3 out)
    char* B_ = L + 16384;            // 16K (L1 out)
    char* C_ = L + 32768;            // 32K (L2 out)
    float* sA = (float*)(L + 65536);
    float* sB = (float*)(L + 65792);
    int blk = bid + 2;
    stage_flows_nb(flows, blk, A_, sA, wv, lane);
    asm volatile("" ::: "memory");   // compiler fence: order stage writes before L1 reads
    sage_layer_nb<128, 128>(A_, B_, sA, sB, WRp + 0,     bl1, wv, lr, lg, l64);
    asm volatile("" ::: "memory");
    sage_layer_nb<128, 256>(B_, C_, sB, sA, WRp + 16384, bl2, wv, lr, lg, l64);
    asm volatile("" ::: "memory");
    sage_layer_nb<256, 128>(C_, A_, sA, sB, WRp + 49152, bl3, wv, lr, lg, l64);
    asm volatile("" ::: "memory");
    sage_layer_last_nb(A_, sB, WRp + 81920, bl4, wv, lr, lg, l64, Fg, blk);
    return;
  }

  // prep_mb path: MBT permuted [d>>4][w][ks][lane][8]
  char* QT  = L;
  char* KTm = L + 32768;
  int w = bid - 510;
  const float* qw = qsa + (size_t)w * 16384;
  const float* kw = ksa + (size_t)w * 16384;
  for (int e = tid; e < 16384; e += 256) {
    int op = e >> 7, c = e & 127;
    int off = c * 256 + ((op * 2) ^ ((c & 7) << 4));
    *reinterpret_cast<ushort*>(QT + off)  = f2b(qw[e]);
    *reinterpret_cast<ushort*>(KTm + off) = f2b(kw[e]);
  }
  __syncthreads();
  #pragma unroll
  for (int rt = 0; rt < 2; ++rt) {
    int e = wv * 32 + rt * 16 + lr;
    bf16x8 a[4];
    #pragma unroll
    for (int ks = 0; ks < 4; ++ks)
      a[ks] = *reinterpret_cast<const bf16x8*>(KTm + e * 256 + ((ks * 64 + lg * 16) ^ ((e & 7) << 4)));
    #pragma unroll
    for (int ct = 0; ct < 8; ++ct) {
      int d = ct * 16 + lr;
      bf16x8 bq[4];
      #pragma unroll
      for (int ks = 0; ks < 4; ++ks)
        bq[ks] = *reinterpret_cast<const bf16x8*>(QT + d * 256 + ((ks * 64 + lg * 16) ^ ((d & 7) << 4)));
      f32x4 acc = {0.f, 0.f, 0.f, 0.f};
      #pragma unroll
      for (int ks = 0; ks < 4; ++ks)
        acc = __builtin_amdgcn_mfma_f32_16x16x32_bf16(a[ks], bq[ks], acc, 0, 0, 0);
      uint2 pk;
      pk.x = (unsigned)f2b(acc[0]) | ((unsigned)f2b(acc[1]) << 16);
      pk.y = (unsigned)f2b(acc[2]) | ((unsigned)f2b(acc[3]) << 16);
      size_t base = ((((size_t)ct * 8 + w) * 4 + wv) * 64 +
                     (size_t)(((rt * 2 + (lg >> 1)) & 3) * 16 + lr)) * 8 + (lg & 1) * 4;
      *reinterpret_cast<uint2*>(&MBT[base]) = pk;
    }
  }
}

// ---------------- attn v6: 512 blocks x 512 thr, dbuf RT, coalesced SBp/MBT ----------------
__global__ __launch_bounds__(512, 4) void attn_fused(
    const ushort* __restrict__ F, const ushort* __restrict__ MBT,
    const ushort* __restrict__ SBp, float* __restrict__ Out) {
  __shared__ char FT[32768];
  __shared__ char RTb[32768];

  const int bq = blockIdx.x;
  const int b = bq >> 1, ph = bq & 1;
  const int tid = threadIdx.x;
  const int l = tid & 63, wv = tid >> 6;
  const int lr = l & 15, lg = l >> 4;

  const ushort* Fb = F + (size_t)b * 16384;

  #pragma unroll
  for (int it = 0; it < 4; ++it) {
    int idx = tid + it * 512;
    int m = idx >> 4, eg = idx & 15;
    uint4 v = *reinterpret_cast<const uint4*>(Fb + m * 128 + eg * 8);
    const ushort* pv = reinterpret_cast<const ushort*>(&v);
    #pragma unroll
    for (int j = 0; j < 8; ++j) {
      int e = eg * 8 + j;
      *reinterpret_cast<ushort*>(FT + e * 256 + ((m * 2) ^ ftswz(e))) = pv[j];
    }
  }

  bf16x8 fa[4];
  {
    int n = wv * 16 + lr;
    #pragma unroll
    for (int ks = 0; ks < 4; ++ks)
      fa[ks] = *reinterpret_cast<const bf16x8*>(Fb + n * 128 + ks * 32 + lg * 8);
  }
  __syncthreads();

  bf16x8 af[4];
  {
    int e = wv * 16 + lr;
    #pragma unroll
    for (int ks = 0; ks < 4; ++ks)
      af[ks] = *reinterpret_cast<const bf16x8*>(
          FT + e * 256 + ((ks * 64 + lg * 16) ^ ftswz(e)));
  }

  f32x4 zacc[4];
  #pragma unroll
  for (int pt = 0; pt < 4; ++pt) zacc[pt] = f32x4{0.f, 0.f, 0.f, 0.f};

  const int eb0 = 2 * (wv * 16 + lg * 4);

  auto Rphase = [&](int w, char* RT) {
    #pragma unroll
    for (int pt = 0; pt < 4; ++pt) {
      int p = pt * 16 + lr;
      bf16x8 bs[4];
      #pragma unroll
      for (int ks = 0; ks < 4; ++ks)
        bs[ks] = *reinterpret_cast<const bf16x8*>(
            SBp + ((((size_t)(w * 2 + ph) * 4 + pt) * 4 + ks) * 64 + l) * 8);
      f32x4 rr = {0.f, 0.f, 0.f, 0.f};
      #pragma unroll
      for (int ks = 0; ks < 4; ++ks)
        rr = __builtin_amdgcn_mfma_f32_16x16x32_bf16(af[ks], bs[ks], rr, 0, 0, 0);
      uint2 pk;
      pk.x = (unsigned)f2b(rr[0]) | ((unsigned)f2b(rr[1]) << 16);
      pk.y = (unsigned)f2b(rr[2]) | ((unsigned)f2b(rr[3]) << 16);
      *reinterpret_cast<uint2*>(RT + p * 256 + (eb0 ^ ((p & 7) << 4))) = pk;
    }
  };
  auto Zphase = [&](int w, const char* RT) {
    bf16x8 mf[4];
    #pragma unroll
    for (int ks = 0; ks < 4; ++ks)
      mf[ks] = *reinterpret_cast<const bf16x8*>(
          MBT + ((((size_t)wv * 8 + w) * 4 + ks) * 64 + l) * 8);
    #pragma unroll
    for (int pt = 0; pt < 4; ++pt) {
      int p = pt * 16 + lr;
      bf16x8 bg[4];
      #pragma unroll
      for (int ks = 0; ks < 4; ++ks)
        bg[ks] = *reinterpret_cast<const bf16x8*>(
            RT + p * 256 + ((ks * 64 + lg * 16) ^ ((p & 7) << 4)));
      #pragma unroll
      for (int ks = 0; ks < 4; ++ks)
        zacc[pt] = __builtin_amdgcn_mfma_f32_16x16x32_bf16(mf[ks], bg[ks], zacc[pt], 0, 0, 0);
    }
  };

  Rphase(0, RTb);
  __syncthreads();
  #pragma unroll
  for (int w = 0; w < 7; ++w) {
    Zphase(w, RTb + (w & 1) * 16384);
    Rphase(w + 1, RTb + ((w + 1) & 1) * 16384);
    __syncthreads();
  }
  Zphase(7, RTb + 16384);
  #pragma unroll
  for (int pt = 0; pt < 4; ++pt) {
    int p = pt * 16 + lr;
    uint2 pk;
    pk.x = (unsigned)f2b(zacc[pt][0]) | ((unsigned)f2b(zacc[pt][1]) << 16);
    pk.y = (unsigned)f2b(zacc[pt][2]) | ((unsigned)f2b(zacc[pt][3]) << 16);
    *reinterpret_cast<uint2*>(RTb + p * 256 + (eb0 ^ ((p & 7) << 4))) = pk;
  }
  __syncthreads();

  const float inv_scale = 0.08838834764831845f;
  float* ob = Out + (size_t)b * 16384 + ph * 64;
  #pragma unroll
  for (int pt = 0; pt < 4; ++pt) {
    int p = pt * 16 + lr;
    bf16x8 bz[4];
    #pragma unroll
    for (int ks = 0; ks < 4; ++ks)
      bz[ks] = *reinterpret_cast<const bf16x8*>(
          RTb + p * 256 + ((ks * 64 + lg * 16) ^ ((p & 7) << 4)));
    f32x4 oa = {0.f, 0.f, 0.f, 0.f};
    #pragma unroll
    for (int ks = 0; ks < 4; ++ks)
      oa = __builtin_amdgcn_mfma_f32_16x16x32_bf16(fa[ks], bz[ks], oa, 0, 0, 0);
    int n0 = wv * 16 + lg * 4;
    #pragma unroll
    for (int r = 0; r < 4; ++r)
      ob[(size_t)(n0 + r) * 128 + p] = oa[r] * inv_scale;
  }
}

extern "C" void kernel_launch(void* const* d_in, const int* in_sizes, int n_in,
                              void* d_out, int out_size, void* d_ws, size_t ws_size,
                              hipStream_t stream) {
  const float* flows = (const float*)d_in[0];
  const float* g1_wl = (const float*)d_in[10];
  const float* g1_bl = (const float*)d_in[11];
  const float* g1_wr = (const float*)d_in[12];
  const float* g2_wl = (const float*)d_in[13];
  const float* g2_bl = (const float*)d_in[14];
  const float* g2_wr = (const float*)d_in[15];
  const float* g3_wl = (const float*)d_in[16];
  const float* g3_bl = (const float*)d_in[17];
  const float* g3_wr = (const float*)d_in[18];
  const float* g4_wl = (const float*)d_in[19];
  const float* g4_bl = (const float*)d_in[20];
  const float* g4_wr = (const float*)d_in[21];
  const float* qsa   = (const float*)d_in[24];
  const float* ksa   = (const float*)d_in[25];
  const float* s2w   = (const float*)d_in[27];
  float* out = (float*)d_out;
  char* wsb  = (char*)d_ws;

  // workspace layout (bytes)
  ushort* FB16 = (ushort*)(wsb);                 // 32768*128 bf16 = 8388608
  ushort* SBp  = (ushort*)(wsb + 8388608);       // 131072 bf16 (permuted)
  ushort* WL   = (ushort*)(wsb + 8650752);       // 98304 bf16
  ushort* WR   = (ushort*)(wsb + 8847360);       // 98304 bf16
  ushort* MBT  = (ushort*)(wsb + 9043968);       // 131072 bf16 (permuted)
  ushort* XT1  = (ushort*)(wsb + 9306112);       // 128*128 bf16
  ushort* XT2  = (ushort*)(wsb + 9338880);       // 256*128 bf16
  ushort* XT3  = (ushort*)(wsb + 9404416);       // 128*128 bf16
  float*  YT4  = (float*)(wsb + 9437184);        // 128*128 f32
  float*  SS   = (float*)(wsb + 9502720);        // 4*128 f32
  ushort* WRp  = (ushort*)(wsb + 9504768);       // 98304 bf16 (permuted)

  prep_all_k<<<896, 256, 0, stream>>>(s2w,
                                      g1_wl, g2_wl, g3_wl, g4_wl,
                                      g1_wr, g2_wr, g3_wr, g4_wr,
                                      SBp, WL, WR, WRp, SS);
  chainL_k<128, 128, 0><<<8, 256, 0, stream>>>(flows, nullptr, nullptr,
                                               WL + 0, WR + 0, g1_bl, XT1, nullptr, SS + 0);
  chainL_k<128, 256, 1><<<16, 256, 0, stream>>>(nullptr, XT1, SS + 0,
                                                WL + 16384, WR + 16384, g2_bl, XT2, nullptr, SS + 128);
  chainL_k<256, 128, 1><<<8, 256, 0, stream>>>(nullptr, XT2, SS + 128,
                                               WL + 49152, WR + 49152, g3_bl, XT3, nullptr, SS + 256);
  chainL_k<128, 128, 2><<<8, 256, 0, stream>>>(nullptr, XT3, SS + 256,
                                               WL + 81920, WR + 81920, g4_bl, nullptr, YT4, SS + 384);
  cl4b_k<<<8, 256, 0, stream>>>(YT4, SS + 384, FB16);
  mega_k<<<518, 256, 0, stream>>>(flows, qsa, ksa, WRp,
                                  g1_bl, g2_bl, g3_bl, g4_bl,
                                  FB16, MBT);
  attn_fused<<<512, 512, 0, stream>>>(FB16, MBT, SBp, out);
}

// Round 25
// 113.231 us; speedup vs baseline: 1.1087x; 1.0430x over previous
//
#include <hip/hip_runtime.h>
#include <math.h>

// Model_6150393168181 — bf16-MFMA pipeline.
// Launches: prep_all (+SS zero) -> prep_mb -> chainL1..L4 -> cl4b -> sage -> attn.
// Math: out[b] = f @ Z / sqrt(128), Z = sum_w MB_w^T (f^T SB_w^T);
//   MB_w[e][d] = sum_o' ksa[w,o',e] qsa[w,o',d];  f = rms(relu(SAGE4(rms(flows))));
//   SAGE agg (rows 0..127): corr_l = L @ (s.X_l @ wl_l^T), L[n][i]=(i<n)/max(n,1).
// v10: sage_k = 510 blocks (<= 512 = 2/CU x 256CU capacity -> SINGLE scheduling round,
// no 6-block tail), launch_bounds(256,2) for VGPR headroom, barrier-free with compiler
// fences. prep_mb_k standalone (8 blocks). All streamed MFMA fragments (WRp, SBp, MBT)
// in wave-coalesced order [tile][ks][lane][8].

typedef __attribute__((ext_vector_type(8))) short bf16x8;
typedef __attribute__((ext_vector_type(4))) float f32x4;

__device__ inline ushort f2b(float x) {
  unsigned u = __builtin_bit_cast(unsigned, x);
  unsigned r = (u + 0x7fffu + ((u >> 16) & 1u)) >> 16;
  return (ushort)r;
}
__device__ inline int ftswz(int e) { return ((e & 7) ^ ((e >> 3) & 15)) << 4; }

// ---------------- prep: SBp (permuted) + WL/WR (row-major) + WRp (permuted) + SS zero ----------------
__global__ __launch_bounds__(256) void prep_all_k(
    const float* __restrict__ s2w,
    const float* __restrict__ wl1, const float* __restrict__ wl2,
    const float* __restrict__ wl3, const float* __restrict__ wl4,
    const float* __restrict__ wr1, const float* __restrict__ wr2,
    const float* __restrict__ wr3, const float* __restrict__ wr4,
    ushort* __restrict__ SBp, ushort* __restrict__ WL, ushort* __restrict__ WR,
    ushort* __restrict__ WRp, float* __restrict__ SS) {
  if (blockIdx.x == 0) {
    SS[threadIdx.x] = 0.f;
    SS[threadIdx.x + 256] = 0.f;
  }
  int i = blockIdx.x * 256 + threadIdx.x;
  if (i < 131072) {
    int w = i >> 14, p = (i >> 7) & 127, m = i & 127;
    int sidx = ((((w * 2 + (p >> 6)) * 4 + ((p >> 4) & 3)) * 4 + (m >> 5)) * 64 +
                ((m >> 3) & 3) * 16 + (p & 15)) * 8 + (m & 7);
    SBp[sidx] = f2b(s2w[p * 1024 + m * 8 + w]);
    return;
  }
  i -= 131072;
  if (i < 98304) {
    float v, u;
    int base, K, col, k;
    if (i < 16384)      { v = wl1[i];         u = wr1[i];         base = 0;     K = 128; col = i >> 7;            k = i & 127; }
    else if (i < 49152) { int j = i - 16384;  v = wl2[j]; u = wr2[j]; base = 16384; K = 128; col = j >> 7;       k = j & 127; }
    else if (i < 81920) { int j = i - 49152;  v = wl3[j]; u = wr3[j]; base = 49152; K = 256; col = j >> 8;       k = j & 255; }
    else                { int j = i - 81920;  v = wl4[j]; u = wr4[j]; base = 81920; K = 128; col = j >> 7;       k = j & 127; }
    WL[i] = f2b(v);
    ushort ub = f2b(u);
    WR[i] = ub;
    int pidx = base + (((col >> 4) * (K / 32) + (k >> 5)) * 64 +
                       ((k >> 3) & 3) * 16 + (col & 15)) * 8 + (k & 7);
    WRp[pidx] = ub;
  }
}

// ---------------- prep_mb: MBT permuted (own kernel, 64K LDS, 8 blocks) ----------------
__global__ __launch_bounds__(256, 1) void prep_mb_k(
    const float* __restrict__ qsa, const float* __restrict__ ksa,
    ushort* __restrict__ MBT) {
  __shared__ char QT[32768];
  __shared__ char KTm[32768];
  const int tid = threadIdx.x;
  const int lane = tid & 63, wv = tid >> 6, lr = lane & 15, lg = lane >> 4;
  int w = blockIdx.x;
  const float* qw = qsa + (size_t)w * 16384;
  const float* kw = ksa + (size_t)w * 16384;
  for (int e = tid; e < 16384; e += 256) {
    int op = e >> 7, c = e & 127;
    int off = c * 256 + ((op * 2) ^ ((c & 7) << 4));
    *reinterpret_cast<ushort*>(QT + off)  = f2b(qw[e]);
    *reinterpret_cast<ushort*>(KTm + off) = f2b(kw[e]);
  }
  __syncthreads();
  #pragma unroll
  for (int rt = 0; rt < 2; ++rt) {
    int e = wv * 32 + rt * 16 + lr;
    bf16x8 a[4];
    #pragma unroll
    for (int ks = 0; ks < 4; ++ks)
      a[ks] = *reinterpret_cast<const bf16x8*>(KTm + e * 256 + ((ks * 64 + lg * 16) ^ ((e & 7) << 4)));
    #pragma unroll
    for (int ct = 0; ct < 8; ++ct) {
      int d = ct * 16 + lr;
      bf16x8 bq[4];
      #pragma unroll
      for (int ks = 0; ks < 4; ++ks)
        bq[ks] = *reinterpret_cast<const bf16x8*>(QT + d * 256 + ((ks * 64 + lg * 16) ^ ((d & 7) << 4)));
      f32x4 acc = {0.f, 0.f, 0.f, 0.f};
      #pragma unroll
      for (int ks = 0; ks < 4; ++ks)
        acc = __builtin_amdgcn_mfma_f32_16x16x32_bf16(a[ks], bq[ks], acc, 0, 0, 0);
      uint2 pk;
      pk.x = (unsigned)f2b(acc[0]) | ((unsigned)f2b(acc[1]) << 16);
      pk.y = (unsigned)f2b(acc[2]) | ((unsigned)f2b(acc[3]) << 16);
      size_t base = ((((size_t)ct * 8 + w) * 4 + wv) * 64 +
                     (size_t)(((rt * 2 + (lg >> 1)) & 3) * 16 + lr)) * 8 + (lg & 1) * 4;
      *reinterpret_cast<uint2*>(&MBT[base]) = pk;
    }
  }
}

// ---------------- chain layer kernel (WL/WR row-major) ----------------
template <int K, int N, int MODE>
__global__ __launch_bounds__(256, 1) void chainL_k(
    const float* __restrict__ flows, const ushort* __restrict__ XTsrc,
    const float* __restrict__ SSprev,
    const ushort* __restrict__ Wl, const ushort* __restrict__ Wr,
    const float* __restrict__ bias,
    ushort* __restrict__ XTdst, float* __restrict__ YTdst, float* __restrict__ SScur) {
  __shared__ char XS[K * 272];
  __shared__ char C0T[4096];
  __shared__ float sArr[128];

  const int tid = threadIdx.x;
  const int lane = tid & 63, wv = tid >> 6, lr = lane & 15, lg = lane >> 4;
  const int cG0 = blockIdx.x * 16;

  if (MODE == 0) {
    #pragma unroll
    for (int it = 0; it < 16; ++it) {
      int idx = tid + it * 256;
      int row = idx >> 5, c4 = idx & 31;
      const float4 v = *reinterpret_cast<const float4*>(flows + (size_t)row * 128 + c4 * 4);
      float ss = v.x * v.x + v.y * v.y + v.z * v.z + v.w * v.w;
      ss += __shfl_xor(ss, 16); ss += __shfl_xor(ss, 8);
      ss += __shfl_xor(ss, 4);  ss += __shfl_xor(ss, 2); ss += __shfl_xor(ss, 1);
      *reinterpret_cast<ushort*>(XS + (c4 * 4 + 0) * 272 + row * 2) = f2b(v.x);
      *reinterpret_cast<ushort*>(XS + (c4 * 4 + 1) * 272 + row * 2) = f2b(v.y);
      *reinterpret_cast<ushort*>(XS + (c4 * 4 + 2) * 272 + row * 2) = f2b(v.z);
      *reinterpret_cast<ushort*>(XS + (c4 * 4 + 3) * 272 + row * 2) = f2b(v.w);
      if ((tid & 31) == 0) sArr[row] = rsqrtf(ss * (1.0f / 128.0f));
    }
  } else {
    for (int e = tid * 8; e < K * 128; e += 2048) {
      uint4 v = *reinterpret_cast<const uint4*>(XTsrc + e);
      *reinterpret_cast<uint4*>(XS + (e >> 7) * 272 + (e & 127) * 2) = v;
    }
    if (tid < 128) sArr[tid] = 1.0f / fmaxf(sqrtf(SSprev[tid]), 1e-12f);
  }
  __syncthreads();

  bf16x8 a[2][K / 32];
  float sr[2][4];
  #pragma unroll
  for (int mt = 0; mt < 2; ++mt) {
    int R = wv * 32 + mt * 16 + lr;
    #pragma unroll
    for (int ks = 0; ks < K / 32; ++ks) {
      union { ushort us[8]; bf16x8 v; } u;
      #pragma unroll
      for (int j = 0; j < 8; ++j)
        u.us[j] = *reinterpret_cast<const ushort*>(XS + (ks * 32 + lg * 8 + j) * 272 + R * 2);
      a[mt][ks] = u.v;
    }
    #pragma unroll
    for (int rr = 0; rr < 4; ++rr) sr[mt][rr] = sArr[wv * 32 + mt * 16 + 4 * lg + rr];
  }

  bf16x8 aL[2][4];
  #pragma unroll
  for (int mt = 0; mt < 2; ++mt) {
    int rowL = wv * 32 + mt * 16 + lr;
    ushort iv = f2b(1.0f / (float)(rowL > 1 ? rowL : 1));
    #pragma unroll
    for (int ks = 0; ks < 4; ++ks)
      #pragma unroll
      for (int j = 0; j < 8; ++j) {
        int k = ks * 32 + lg * 8 + j;
        aL[mt][ks][j] = (short)((k < rowL) ? iv : 0);
      }
  }

  const int cG = cG0 + lr;
  {
    bf16x8 bw[K / 32];
    #pragma unroll
    for (int ks = 0; ks < K / 32; ++ks)
      bw[ks] = *reinterpret_cast<const bf16x8*>(Wl + (size_t)cG * K + ks * 32 + lg * 8);
    #pragma unroll
    for (int mt = 0; mt < 2; ++mt) {
      f32x4 acc = {0.f, 0.f, 0.f, 0.f};
      #pragma unroll
      for (int ks = 0; ks < K / 32; ++ks)
        acc = __builtin_amdgcn_mfma_f32_16x16x32_bf16(a[mt][ks], bw[ks], acc, 0, 0, 0);
      int m0 = wv * 32 + mt * 16 + lg * 4;
      uint2 pk;
      pk.x = (unsigned)f2b(acc[0] * sr[mt][0]) | ((unsigned)f2b(acc[1] * sr[mt][1]) << 16);
      pk.y = (unsigned)f2b(acc[2] * sr[mt][2]) | ((unsigned)f2b(acc[3] * sr[mt][3]) << 16);
      *reinterpret_cast<uint2*>(C0T + lr * 256 + ((2 * m0) ^ ((lr & 7) << 4))) = pk;
    }
  }
  __syncthreads();

  {
    bf16x8 bc[4], bw[K / 32];
    #pragma unroll
    for (int ks = 0; ks < 4; ++ks)
      bc[ks] = *reinterpret_cast<const bf16x8*>(C0T + lr * 256 + ((ks * 64 + lg * 16) ^ ((lr & 7) << 4)));
    #pragma unroll
    for (int ks = 0; ks < K / 32; ++ks)
      bw[ks] = *reinterpret_cast<const bf16x8*>(Wr + (size_t)cG * K + ks * 32 + lg * 8);
    float bb = bias[cG];
    #pragma unroll
    for (int mt = 0; mt < 2; ++mt) {
      f32x4 cacc = {0.f, 0.f, 0.f, 0.f}, acc = {0.f, 0.f, 0.f, 0.f};
      #pragma unroll
      for (int ks = 0; ks < 4; ++ks)
        cacc = __builtin_amdgcn_mfma_f32_16x16x32_bf16(aL[mt][ks], bc[ks], cacc, 0, 0, 0);
      #pragma unroll
      for (int ks = 0; ks < K / 32; ++ks)
        acc = __builtin_amdgcn_mfma_f32_16x16x32_bf16(a[mt][ks], bw[ks], acc, 0, 0, 0);
      int m0 = wv * 32 + mt * 16 + lg * 4;
      float ssq[4];
      if (MODE < 2) {
        float y0 = acc[0] * sr[mt][0] + bb + cacc[0];
        float y1 = acc[1] * sr[mt][1] + bb + cacc[1];
        float y2 = acc[2] * sr[mt][2] + bb + cacc[2];
        float y3 = acc[3] * sr[mt][3] + bb + cacc[3];
        uint2 pk;
        pk.x = (unsigned)f2b(y0) | ((unsigned)f2b(y1) << 16);
        pk.y = (unsigned)f2b(y2) | ((unsigned)f2b(y3) << 16);
        *reinterpret_cast<uint2*>(&XTdst[(size_t)cG * 128 + m0]) = pk;
        ssq[0] = y0 * y0; ssq[1] = y1 * y1; ssq[2] = y2 * y2; ssq[3] = y3 * y3;
      } else {
        float4 vv;
        vv.x = fmaxf(acc[0] * sr[mt][0] + bb + cacc[0], 0.f);
        vv.y = fmaxf(acc[1] * sr[mt][1] + bb + cacc[1], 0.f);
        vv.z = fmaxf(acc[2] * sr[mt][2] + bb + cacc[2], 0.f);
        vv.w = fmaxf(acc[3] * sr[mt][3] + bb + cacc[3], 0.f);
        *reinterpret_cast<float4*>(&YTdst[(size_t)cG * 128 + m0]) = vv;
        ssq[0] = vv.x * vv.x; ssq[1] = vv.y * vv.y; ssq[2] = vv.z * vv.z; ssq[3] = vv.w * vv.w;
      }
      #pragma unroll
      for (int rr = 0; rr < 4; ++rr) {
        float ss = ssq[rr];
        ss += __shfl_xor(ss, 1); ss += __shfl_xor(ss, 2);
        ss += __shfl_xor(ss, 4); ss += __shfl_xor(ss, 8);
        if (lr == 0) atomicAdd(&SScur[m0 + rr], ss);
      }
    }
  }
}

// ---------------- cl4b ----------------
__global__ __launch_bounds__(256) void cl4b_k(
    const float* __restrict__ YT, const float* __restrict__ SS4,
    ushort* __restrict__ Fg) {
  int t = blockIdx.x * 256 + threadIdx.x;
  int r = t >> 4, cs = t & 15;
  float sc = sqrtf(128.0f / fmaxf(SS4[r], 1e-20f));
  ushort tmp[8];
  #pragma unroll
  for (int j = 0; j < 8; ++j) {
    int c = cs * 8 + j;
    tmp[j] = f2b(YT[(size_t)c * 128 + r] * sc);
  }
  *reinterpret_cast<uint4*>(&Fg[(size_t)r * 128 + cs * 8]) = *reinterpret_cast<uint4*>(tmp);
}

// ---------------- sage helpers (barrier-free, wave-private rows) ----------------
__device__ inline void stage_flows_nb(const float* __restrict__ flows, int blk,
                                      char* A_, float* sArr, int wv, int lane) {
  int r2 = lane >> 5;
  int c4 = lane & 31;
  #pragma unroll
  for (int it = 0; it < 8; ++it) {
    int rowbase = wv * 16 + it * 2;
    const float4 v = *reinterpret_cast<const float4*>(
        flows + ((size_t)blk * 64 + rowbase) * 128 + lane * 4);
    int row = rowbase + r2;
    float ss = v.x * v.x + v.y * v.y + v.z * v.z + v.w * v.w;
    ss += __shfl_xor(ss, 16); ss += __shfl_xor(ss, 8);
    ss += __shfl_xor(ss, 4);  ss += __shfl_xor(ss, 2); ss += __shfl_xor(ss, 1);
    uint2 pk;
    pk.x = (unsigned)f2b(v.x) | ((unsigned)f2b(v.y) << 16);
    pk.y = (unsigned)f2b(v.z) | ((unsigned)f2b(v.w) << 16);
    *reinterpret_cast<uint2*>(A_ + row * 256 + ((c4 * 8) ^ ((row & 7) << 4))) = pk;
    if (c4 == 0) sArr[row] = rsqrtf(ss * (1.0f / 128.0f));
  }
}

template <int K, int N>
__device__ inline void sage_layer_nb(const char* Xsrc, char* Xdst,
                                     const float* sP, float* sN,
                                     const ushort* __restrict__ Wrp,
                                     const float* __restrict__ bias,
                                     int wv, int lr, int lg, int l64) {
  bf16x8 a[K / 32];
  float sr[4];
  int rowA = wv * 16 + lr;
  #pragma unroll
  for (int ks = 0; ks < K / 32; ++ks)
    a[ks] = *reinterpret_cast<const bf16x8*>(
        Xsrc + rowA * (K * 2) + ((ks * 64 + lg * 16) ^ ((rowA & 7) << 4)));
  #pragma unroll
  for (int rr = 0; rr < 4; ++rr) sr[rr] = sP[wv * 16 + 4 * lg + rr];
  float ssq[4] = {0.f, 0.f, 0.f, 0.f};
  #pragma unroll
  for (int nt = 0; nt < N / 16; ++nt) {
    int col = nt * 16 + lr;
    bf16x8 b[K / 32];
    #pragma unroll
    for (int ks = 0; ks < K / 32; ++ks)
      b[ks] = *reinterpret_cast<const bf16x8*>(Wrp + (((size_t)nt * (K / 32) + ks) * 64 + l64) * 8);
    f32x4 acc = {0.f, 0.f, 0.f, 0.f};
    #pragma unroll
    for (int ks = 0; ks < K / 32; ++ks)
      acc = __builtin_amdgcn_mfma_f32_16x16x32_bf16(a[ks], b[ks], acc, 0, 0, 0);
    float bb = bias[col];
    #pragma unroll
    for (int rr = 0; rr < 4; ++rr) {
      int row = wv * 16 + 4 * lg + rr;
      float y = acc[rr] * sr[rr] + bb;
      *reinterpret_cast<ushort*>(Xdst + row * (N * 2) + ((col * 2) ^ ((row & 7) << 4))) = f2b(y);
      ssq[rr] += y * y;
    }
  }
  #pragma unroll
  for (int rr = 0; rr < 4; ++rr) {
    float ss = ssq[rr];
    ss += __shfl_xor(ss, 1); ss += __shfl_xor(ss, 2);
    ss += __shfl_xor(ss, 4); ss += __shfl_xor(ss, 8);
    if (lr == 0) sN[wv * 16 + 4 * lg + rr] = 1.0f / fmaxf(sqrtf(ss), 1e-12f);
  }
}

__device__ inline void sage_layer_last_nb(const char* Xsrc, const float* sP,
                                          const ushort* __restrict__ Wrp,
                                          const float* __restrict__ bias,
                                          int wv, int lr, int lg, int l64,
                                          ushort* __restrict__ Fg, int blk) {
  bf16x8 a[4];
  float sr[4];
  int rowA = wv * 16 + lr;
  #pragma unroll
  for (int ks = 0; ks < 4; ++ks)
    a[ks] = *reinterpret_cast<const bf16x8*>(
        Xsrc + rowA * 256 + ((ks * 64 + lg * 16) ^ ((rowA & 7) << 4)));
  #pragma unroll
  for (int rr = 0; rr < 4; ++rr) sr[rr] = sP[wv * 16 + 4 * lg + rr];
  float yreg[8][4];
  float ssq[4] = {0.f, 0.f, 0.f, 0.f};
  #pragma unroll
  for (int nt = 0; nt < 8; ++nt) {
    int col = nt * 16 + lr;
    bf16x8 b[4];
    #pragma unroll
    for (int ks = 0; ks < 4; ++ks)
      b[ks] = *reinterpret_cast<const bf16x8*>(Wrp + (((size_t)nt * 4 + ks) * 64 + l64) * 8);
    f32x4 acc = {0.f, 0.f, 0.f, 0.f};
    #pragma unroll
    for (int ks = 0; ks < 4; ++ks)
      acc = __builtin_amdgcn_mfma_f32_16x16x32_bf16(a[ks], b[ks], acc, 0, 0, 0);
    float bb = bias[col];
    #pragma unroll
    for (int rr = 0; rr < 4; ++rr) {
      float y = acc[rr] * sr[rr] + bb;
      yreg[nt][rr] = y;
      float v = fmaxf(y, 0.f);
      ssq[rr] += v * v;
    }
  }
  float sc[4];
  #pragma unroll
  for (int rr = 0; rr < 4; ++rr) {
    float ss = ssq[rr];
    ss += __shfl_xor(ss, 1); ss += __shfl_xor(ss, 2);
    ss += __shfl_xor(ss, 4); ss += __shfl_xor(ss, 8);
    sc[rr] = sqrtf(128.0f / fmaxf(ss, 1e-20f));
  }
  #pragma unroll
  for (int nt = 0; nt < 8; ++nt)
    #pragma unroll
    for (int rr = 0; rr < 4; ++rr) {
      int row = wv * 16 + 4 * lg + rr;
      Fg[((size_t)blk * 64 + row) * 128 + nt * 16 + lr] = f2b(fmaxf(yreg[nt][rr], 0.f) * sc[rr]);
    }
}

// ---------------- sage kernel: 510 blocks (single scheduling round), barrier-free ----------------
__global__ __launch_bounds__(256, 2) void sage_k(
    const float* __restrict__ flows,
    const ushort* __restrict__ WRp,
    const float* __restrict__ bl1, const float* __restrict__ bl2,
    const float* __restrict__ bl3, const float* __restrict__ bl4,
    ushort* __restrict__ Fg) {
  __shared__ char A_[16384];
  __shared__ char B_[16384];
  __shared__ char C_[32768];
  __shared__ float sA[64], sB[64];
  const int tid = threadIdx.x;
  const int lane = tid & 63, wv = tid >> 6, lr = lane & 15, lg = lane >> 4;
  const int l64 = lane;
  int blk = blockIdx.x + 2;
  stage_flows_nb(flows, blk, A_, sA, wv, lane);
  asm volatile("" ::: "memory");
  sage_layer_nb<128, 128>(A_, B_, sA, sB, WRp + 0,     bl1, wv, lr, lg, l64);
  asm volatile("" ::: "memory");
  sage_layer_nb<128, 256>(B_, C_, sB, sA, WRp + 16384, bl2, wv, lr, lg, l64);
  asm volatile("" ::: "memory");
  sage_layer_nb<256, 128>(C_, A_, sA, sB, WRp + 49152, bl3, wv, lr, lg, l64);
  asm volatile("" ::: "memory");
  sage_layer_last_nb(A_, sB, WRp + 81920, bl4, wv, lr, lg, l64, Fg, blk);
}

// ---------------- attn v6: 512 blocks x 512 thr, dbuf RT, coalesced SBp/MBT ----------------
__global__ __launch_bounds__(512, 4) void attn_fused(
    const ushort* __restrict__ F, const ushort* __restrict__ MBT,
    const ushort* __restrict__ SBp, float* __restrict__ Out) {
  __shared__ char FT[32768];
  __shared__ char RTb[32768];

  const int bq = blockIdx.x;
  const int b = bq >> 1, ph = bq & 1;
  const int tid = threadIdx.x;
  const int l = tid & 63, wv = tid >> 6;
  const int lr = l & 15, lg = l >> 4;

  const ushort* Fb = F + (size_t)b * 16384;

  #pragma unroll
  for (int it = 0; it < 4; ++it) {
    int idx = tid + it * 512;
    int m = idx >> 4, eg = idx & 15;
    uint4 v = *reinterpret_cast<const uint4*>(Fb + m * 128 + eg * 8);
    const ushort* pv = reinterpret_cast<const ushort*>(&v);
    #pragma unroll
    for (int j = 0; j < 8; ++j) {
      int e = eg * 8 + j;
      *reinterpret_cast<ushort*>(FT + e * 256 + ((m * 2) ^ ftswz(e))) = pv[j];
    }
  }

  bf16x8 fa[4];
  {
    int n = wv * 16 + lr;
    #pragma unroll
    for (int ks = 0; ks < 4; ++ks)
      fa[ks] = *reinterpret_cast<const bf16x8*>(Fb + n * 128 + ks * 32 + lg * 8);
  }
  __syncthreads();

  bf16x8 af[4];
  {
    int e = wv * 16 + lr;
    #pragma unroll
    for (int ks = 0; ks < 4; ++ks)
      af[ks] = *reinterpret_cast<const bf16x8*>(
          FT + e * 256 + ((ks * 64 + lg * 16) ^ ftswz(e)));
  }

  f32x4 zacc[4];
  #pragma unroll
  for (int pt = 0; pt < 4; ++pt) zacc[pt] = f32x4{0.f, 0.f, 0.f, 0.f};

  const int eb0 = 2 * (wv * 16 + lg * 4);

  auto Rphase = [&](int w, char* RT) {
    #pragma unroll
    for (int pt = 0; pt < 4; ++pt) {
      int p = pt * 16 + lr;
      bf16x8 bs[4];
      #pragma unroll
      for (int ks = 0; ks < 4; ++ks)
        bs[ks] = *reinterpret_cast<const bf16x8*>(
            SBp + ((((size_t)(w * 2 + ph) * 4 + pt) * 4 + ks) * 64 + l) * 8);
      f32x4 rr = {0.f, 0.f, 0.f, 0.f};
      #pragma unroll
      for (int ks = 0; ks < 4; ++ks)
        rr = __builtin_amdgcn_mfma_f32_16x16x32_bf16(af[ks], bs[ks], rr, 0, 0, 0);
      uint2 pk;
      pk.x = (unsigned)f2b(rr[0]) | ((unsigned)f2b(rr[1]) << 16);
      pk.y = (unsigned)f2b(rr[2]) | ((unsigned)f2b(rr[3]) << 16);
      *reinterpret_cast<uint2*>(RT + p * 256 + (eb0 ^ ((p & 7) << 4))) = pk;
    }
  };
  auto Zphase = [&](int w, const char* RT) {
    bf16x8 mf[4];
    #pragma unroll
    for (int ks = 0; ks < 4; ++ks)
      mf[ks] = *reinterpret_cast<const bf16x8*>(
          MBT + ((((size_t)wv * 8 + w) * 4 + ks) * 64 + l) * 8);
    #pragma unroll
    for (int pt = 0; pt < 4; ++pt) {
      int p = pt * 16 + lr;
      bf16x8 bg[4];
      #pragma unroll
      for (int ks = 0; ks < 4; ++ks)
        bg[ks] = *reinterpret_cast<const bf16x8*>(
            RT + p * 256 + ((ks * 64 + lg * 16) ^ ((p & 7) << 4)));
      #pragma unroll
      for (int ks = 0; ks < 4; ++ks)
        zacc[pt] = __builtin_amdgcn_mfma_f32_16x16x32_bf16(mf[ks], bg[ks], zacc[pt], 0, 0, 0);
    }
  };

  Rphase(0, RTb);
  __syncthreads();
  #pragma unroll
  for (int w = 0; w < 7; ++w) {
    Zphase(w, RTb + (w & 1) * 16384);
    Rphase(w + 1, RTb + ((w + 1) & 1) * 16384);
    __syncthreads();
  }
  Zphase(7, RTb + 16384);
  #pragma unroll
  for (int pt = 0; pt < 4; ++pt) {
    int p = pt * 16 + lr;
    uint2 pk;
    pk.x = (unsigned)f2b(zacc[pt][0]) | ((unsigned)f2b(zacc[pt][1]) << 16);
    pk.y = (unsigned)f2b(zacc[pt][2]) | ((unsigned)f2b(zacc[pt][3]) << 16);
    *reinterpret_cast<uint2*>(RTb + p * 256 + (eb0 ^ ((p & 7) << 4))) = pk;
  }
  __syncthreads();

  const float inv_scale = 0.08838834764831845f;
  float* ob = Out + (size_t)b * 16384 + ph * 64;
  #pragma unroll
  for (int pt = 0; pt < 4; ++pt) {
    int p = pt * 16 + lr;
    bf16x8 bz[4];
    #pragma unroll
    for (int ks = 0; ks < 4; ++ks)
      bz[ks] = *reinterpret_cast<const bf16x8*>(
          RTb + p * 256 + ((ks * 64 + lg * 16) ^ ((p & 7) << 4)));
    f32x4 oa = {0.f, 0.f, 0.f, 0.f};
    #pragma unroll
    for (int ks = 0; ks < 4; ++ks)
      oa = __builtin_amdgcn_mfma_f32_16x16x32_bf16(fa[ks], bz[ks], oa, 0, 0, 0);
    int n0 = wv * 16 + lg * 4;
    #pragma unroll
    for (int r = 0; r < 4; ++r)
      ob[(size_t)(n0 + r) * 128 + p] = oa[r] * inv_scale;
  }
}

extern "C" void kernel_launch(void* const* d_in, const int* in_sizes, int n_in,
                              void* d_out, int out_size, void* d_ws, size_t ws_size,
                              hipStream_t stream) {
  const float* flows = (const float*)d_in[0];
  const float* g1_wl = (const float*)d_in[10];
  const float* g1_bl = (const float*)d_in[11];
  const float* g1_wr = (const float*)d_in[12];
  const float* g2_wl = (const float*)d_in[13];
  const float* g2_bl = (const float*)d_in[14];
  const float* g2_wr = (const float*)d_in[15];
  const float* g3_wl = (const float*)d_in[16];
  const float* g3_bl = (const float*)d_in[17];
  const float* g3_wr = (const float*)d_in[18];
  const float* g4_wl = (const float*)d_in[19];
  const float* g4_bl = (const float*)d_in[20];
  const float* g4_wr = (const float*)d_in[21];
  const float* qsa   = (const float*)d_in[24];
  const float* ksa   = (const float*)d_in[25];
  const float* s2w   = (const float*)d_in[27];
  float* out = (float*)d_out;
  char* wsb  = (char*)d_ws;

  // workspace layout (bytes)
  ushort* FB16 = (ushort*)(wsb);                 // 32768*128 bf16 = 8388608
  ushort* SBp  = (ushort*)(wsb + 8388608);       // 131072 bf16 (permuted)
  ushort* WL   = (ushort*)(wsb + 8650752);       // 98304 bf16
  ushort* WR   = (ushort*)(wsb + 8847360);       // 98304 bf16
  ushort* MBT  = (ushort*)(wsb + 9043968);       // 131072 bf16 (permuted)
  ushort* XT1  = (ushort*)(wsb + 9306112);       // 128*128 bf16
  ushort* XT2  = (ushort*)(wsb + 9338880);       // 256*128 bf16
  ushort* XT3  = (ushort*)(wsb + 9404416);       // 128*128 bf16
  float*  YT4  = (float*)(wsb + 9437184);        // 128*128 f32
  float*  SS   = (float*)(wsb + 9502720);        // 4*128 f32
  ushort* WRp  = (ushort*)(wsb + 9504768);       // 98304 bf16 (permuted)

  prep_all_k<<<896, 256, 0, stream>>>(s2w,
                                      g1_wl, g2_wl, g3_wl, g4_wl,
                                      g1_wr, g2_wr, g3_wr, g4_wr,
                                      SBp, WL, WR, WRp, SS);
  prep_mb_k<<<8, 256, 0, stream>>>(qsa, ksa, MBT);
  chainL_k<128, 128, 0><<<8, 256, 0, stream>>>(flows, nullptr, nullptr,
                                               WL + 0, WR + 0, g1_bl, XT1, nullptr, SS + 0);
  chainL_k<128, 256, 1><<<16, 256, 0, stream>>>(nullptr, XT1, SS + 0,
                                                WL + 16384, WR + 16384, g2_bl, XT2, nullptr, SS + 128);
  chainL_k<256, 128, 1><<<8, 256, 0, stream>>>(nullptr, XT2, SS + 128,
                                               WL + 49152, WR + 49152, g3_bl, XT3, nullptr, SS + 256);
  chainL_k<128, 128, 2><<<8, 256, 0, stream>>>(nullptr, XT3, SS + 256,
                                               WL + 81920, WR + 81920, g4_bl, nullptr, YT4, SS + 384);
  cl4b_k<<<8, 256, 0, stream>>>(YT4, SS + 384, FB16);
  sage_k<<<510, 256, 0, stream>>>(flows, WRp, g1_bl, g2_bl, g3_bl, g4_bl, FB16);
  attn_fused<<<512, 512, 0, stream>>>(FB16, MBT, SBp, out);
}

// Round 26
// 86.746 us; speedup vs baseline: 1.4472x; 1.3053x over previous
//
#include <hip/hip_runtime.h>
#include <math.h>

// Model_6150393168181 — bf16-MFMA pipeline, 3 launches.
//   prep_all: weight conversions (SBp/WL/WR/WRp) + SS/CTR zero
//   mega2:    blocks 0..15 = batch-0 chain (4 layers + cl4b, device-counter sync),
//             16..23 = prep_mb (MBT), 24..533 = sage rows 128.. (barrier-free)
//   attn:     Z-route attention
// Math: out[b] = f @ Z / sqrt(128), Z = sum_w MB_w^T (f^T SB_w^T);
//   MB_w[e][d] = sum_o' ksa[w,o',e] qsa[w,o',d];  f = rms(relu(SAGE4(rms(flows))));
//   SAGE agg (rows 0..127): corr_l = L @ (s.X_l @ wl_l^T), L[n][i]=(i<n)/max(n,1).
// Chain sync: producers __threadfence + release atomicAdd on CTR[layer]; all 16 chain
// blocks acquire-spin. Only chain blocks participate -> co-resident (16<<512), no deadlock.

typedef __attribute__((ext_vector_type(8))) short bf16x8;
typedef __attribute__((ext_vector_type(4))) float f32x4;

__device__ inline ushort f2b(float x) {
  unsigned u = __builtin_bit_cast(unsigned, x);
  unsigned r = (u + 0x7fffu + ((u >> 16) & 1u)) >> 16;
  return (ushort)r;
}
__device__ inline int ftswz(int e) { return ((e & 7) ^ ((e >> 3) & 15)) << 4; }

__device__ inline void ctr_signal(unsigned* c) {
  __threadfence();
  __syncthreads();
  if (threadIdx.x == 0)
    __hip_atomic_fetch_add(c, 1u, __ATOMIC_RELEASE, __HIP_MEMORY_SCOPE_AGENT);
}
__device__ inline void ctr_wait(unsigned* c, unsigned tgt) {
  if (threadIdx.x == 0) {
    while (__hip_atomic_load(c, __ATOMIC_ACQUIRE, __HIP_MEMORY_SCOPE_AGENT) < tgt)
      __builtin_amdgcn_s_sleep(8);
  }
  __syncthreads();
}

// ---------------- prep: SBp + WL/WR + WRp + SS/CTR zero ----------------
__global__ __launch_bounds__(256) void prep_all_k(
    const float* __restrict__ s2w,
    const float* __restrict__ wl1, const float* __restrict__ wl2,
    const float* __restrict__ wl3, const float* __restrict__ wl4,
    const float* __restrict__ wr1, const float* __restrict__ wr2,
    const float* __restrict__ wr3, const float* __restrict__ wr4,
    ushort* __restrict__ SBp, ushort* __restrict__ WL, ushort* __restrict__ WR,
    ushort* __restrict__ WRp, float* __restrict__ SS, unsigned* __restrict__ CTR) {
  if (blockIdx.x == 0) {
    SS[threadIdx.x] = 0.f;
    SS[threadIdx.x + 256] = 0.f;
    if (threadIdx.x < 8) CTR[threadIdx.x] = 0u;
  }
  int i = blockIdx.x * 256 + threadIdx.x;
  if (i < 131072) {
    int w = i >> 14, p = (i >> 7) & 127, m = i & 127;
    int sidx = ((((w * 2 + (p >> 6)) * 4 + ((p >> 4) & 3)) * 4 + (m >> 5)) * 64 +
                ((m >> 3) & 3) * 16 + (p & 15)) * 8 + (m & 7);
    SBp[sidx] = f2b(s2w[p * 1024 + m * 8 + w]);
    return;
  }
  i -= 131072;
  if (i < 98304) {
    float v, u;
    int base, K, col, k;
    if (i < 16384)      { v = wl1[i];         u = wr1[i];         base = 0;     K = 128; col = i >> 7;            k = i & 127; }
    else if (i < 49152) { int j = i - 16384;  v = wl2[j]; u = wr2[j]; base = 16384; K = 128; col = j >> 7;       k = j & 127; }
    else if (i < 81920) { int j = i - 49152;  v = wl3[j]; u = wr3[j]; base = 49152; K = 256; col = j >> 8;       k = j & 255; }
    else                { int j = i - 81920;  v = wl4[j]; u = wr4[j]; base = 81920; K = 128; col = j >> 7;       k = j & 127; }
    WL[i] = f2b(v);
    ushort ub = f2b(u);
    WR[i] = ub;
    int pidx = base + (((col >> 4) * (K / 32) + (k >> 5)) * 64 +
                       ((k >> 3) & 3) * 16 + (col & 15)) * 8 + (k & 7);
    WRp[pidx] = ub;
  }
}

// ---------------- chain layer device fn (one 16-col block slice) ----------------
template <int K, int N, int MODE>
__device__ void chain_dev(char* XS, char* C0T, float* sArr,
                          const float* __restrict__ flows, const ushort* __restrict__ XTsrc,
                          const float* __restrict__ SSprev,
                          const ushort* __restrict__ Wl, const ushort* __restrict__ Wr,
                          const float* __restrict__ bias,
                          ushort* __restrict__ XTdst, float* __restrict__ YTdst,
                          float* __restrict__ SScur, int cbid) {
  const int tid = threadIdx.x;
  const int lane = tid & 63, wv = tid >> 6, lr = lane & 15, lg = lane >> 4;
  const int cG0 = cbid * 16;

  if (MODE == 0) {
    #pragma unroll
    for (int it = 0; it < 16; ++it) {
      int idx = tid + it * 256;
      int row = idx >> 5, c4 = idx & 31;
      const float4 v = *reinterpret_cast<const float4*>(flows + (size_t)row * 128 + c4 * 4);
      float ss = v.x * v.x + v.y * v.y + v.z * v.z + v.w * v.w;
      ss += __shfl_xor(ss, 16); ss += __shfl_xor(ss, 8);
      ss += __shfl_xor(ss, 4);  ss += __shfl_xor(ss, 2); ss += __shfl_xor(ss, 1);
      *reinterpret_cast<ushort*>(XS + (c4 * 4 + 0) * 272 + row * 2) = f2b(v.x);
      *reinterpret_cast<ushort*>(XS + (c4 * 4 + 1) * 272 + row * 2) = f2b(v.y);
      *reinterpret_cast<ushort*>(XS + (c4 * 4 + 2) * 272 + row * 2) = f2b(v.z);
      *reinterpret_cast<ushort*>(XS + (c4 * 4 + 3) * 272 + row * 2) = f2b(v.w);
      if ((tid & 31) == 0) sArr[row] = rsqrtf(ss * (1.0f / 128.0f));
    }
  } else {
    for (int e = tid * 8; e < K * 128; e += 2048) {
      uint4 v = *reinterpret_cast<const uint4*>(XTsrc + e);
      *reinterpret_cast<uint4*>(XS + (e >> 7) * 272 + (e & 127) * 2) = v;
    }
    if (tid < 128) sArr[tid] = 1.0f / fmaxf(sqrtf(SSprev[tid]), 1e-12f);
  }
  __syncthreads();

  bf16x8 a[2][K / 32];
  float sr[2][4];
  #pragma unroll
  for (int mt = 0; mt < 2; ++mt) {
    int R = wv * 32 + mt * 16 + lr;
    #pragma unroll
    for (int ks = 0; ks < K / 32; ++ks) {
      union { ushort us[8]; bf16x8 v; } u;
      #pragma unroll
      for (int j = 0; j < 8; ++j)
        u.us[j] = *reinterpret_cast<const ushort*>(XS + (ks * 32 + lg * 8 + j) * 272 + R * 2);
      a[mt][ks] = u.v;
    }
    #pragma unroll
    for (int rr = 0; rr < 4; ++rr) sr[mt][rr] = sArr[wv * 32 + mt * 16 + 4 * lg + rr];
  }

  bf16x8 aL[2][4];
  #pragma unroll
  for (int mt = 0; mt < 2; ++mt) {
    int rowL = wv * 32 + mt * 16 + lr;
    ushort iv = f2b(1.0f / (float)(rowL > 1 ? rowL : 1));
    #pragma unroll
    for (int ks = 0; ks < 4; ++ks)
      #pragma unroll
      for (int j = 0; j < 8; ++j) {
        int k = ks * 32 + lg * 8 + j;
        aL[mt][ks][j] = (short)((k < rowL) ? iv : 0);
      }
  }

  const int cG = cG0 + lr;
  {
    bf16x8 bw[K / 32];
    #pragma unroll
    for (int ks = 0; ks < K / 32; ++ks)
      bw[ks] = *reinterpret_cast<const bf16x8*>(Wl + (size_t)cG * K + ks * 32 + lg * 8);
    #pragma unroll
    for (int mt = 0; mt < 2; ++mt) {
      f32x4 acc = {0.f, 0.f, 0.f, 0.f};
      #pragma unroll
      for (int ks = 0; ks < K / 32; ++ks)
        acc = __builtin_amdgcn_mfma_f32_16x16x32_bf16(a[mt][ks], bw[ks], acc, 0, 0, 0);
      int m0 = wv * 32 + mt * 16 + lg * 4;
      uint2 pk;
      pk.x = (unsigned)f2b(acc[0] * sr[mt][0]) | ((unsigned)f2b(acc[1] * sr[mt][1]) << 16);
      pk.y = (unsigned)f2b(acc[2] * sr[mt][2]) | ((unsigned)f2b(acc[3] * sr[mt][3]) << 16);
      *reinterpret_cast<uint2*>(C0T + lr * 256 + ((2 * m0) ^ ((lr & 7) << 4))) = pk;
    }
  }
  __syncthreads();

  {
    bf16x8 bc[4], bw[K / 32];
    #pragma unroll
    for (int ks = 0; ks < 4; ++ks)
      bc[ks] = *reinterpret_cast<const bf16x8*>(C0T + lr * 256 + ((ks * 64 + lg * 16) ^ ((lr & 7) << 4)));
    #pragma unroll
    for (int ks = 0; ks < K / 32; ++ks)
      bw[ks] = *reinterpret_cast<const bf16x8*>(Wr + (size_t)cG * K + ks * 32 + lg * 8);
    float bb = bias[cG];
    #pragma unroll
    for (int mt = 0; mt < 2; ++mt) {
      f32x4 cacc = {0.f, 0.f, 0.f, 0.f}, acc = {0.f, 0.f, 0.f, 0.f};
      #pragma unroll
      for (int ks = 0; ks < 4; ++ks)
        cacc = __builtin_amdgcn_mfma_f32_16x16x32_bf16(aL[mt][ks], bc[ks], cacc, 0, 0, 0);
      #pragma unroll
      for (int ks = 0; ks < K / 32; ++ks)
        acc = __builtin_amdgcn_mfma_f32_16x16x32_bf16(a[mt][ks], bw[ks], acc, 0, 0, 0);
      int m0 = wv * 32 + mt * 16 + lg * 4;
      float ssq[4];
      if (MODE < 2) {
        float y0 = acc[0] * sr[mt][0] + bb + cacc[0];
        float y1 = acc[1] * sr[mt][1] + bb + cacc[1];
        float y2 = acc[2] * sr[mt][2] + bb + cacc[2];
        float y3 = acc[3] * sr[mt][3] + bb + cacc[3];
        uint2 pk;
        pk.x = (unsigned)f2b(y0) | ((unsigned)f2b(y1) << 16);
        pk.y = (unsigned)f2b(y2) | ((unsigned)f2b(y3) << 16);
        *reinterpret_cast<uint2*>(&XTdst[(size_t)cG * 128 + m0]) = pk;
        ssq[0] = y0 * y0; ssq[1] = y1 * y1; ssq[2] = y2 * y2; ssq[3] = y3 * y3;
      } else {
        float4 vv;
        vv.x = fmaxf(acc[0] * sr[mt][0] + bb + cacc[0], 0.f);
        vv.y = fmaxf(acc[1] * sr[mt][1] + bb + cacc[1], 0.f);
        vv.z = fmaxf(acc[2] * sr[mt][2] + bb + cacc[2], 0.f);
        vv.w = fmaxf(acc[3] * sr[mt][3] + bb + cacc[3], 0.f);
        *reinterpret_cast<float4*>(&YTdst[(size_t)cG * 128 + m0]) = vv;
        ssq[0] = vv.x * vv.x; ssq[1] = vv.y * vv.y; ssq[2] = vv.z * vv.z; ssq[3] = vv.w * vv.w;
      }
      #pragma unroll
      for (int rr = 0; rr < 4; ++rr) {
        float ss = ssq[rr];
        ss += __shfl_xor(ss, 1); ss += __shfl_xor(ss, 2);
        ss += __shfl_xor(ss, 4); ss += __shfl_xor(ss, 8);
        if (lr == 0) atomicAdd(&SScur[m0 + rr], ss);
      }
    }
  }
}

// ---------------- sage helpers (barrier-free, wave-private rows) ----------------
__device__ inline void stage_flows_nb(const float* __restrict__ flows, int blk,
                                      char* A_, float* sArr, int wv, int lane) {
  int r2 = lane >> 5;
  int c4 = lane & 31;
  #pragma unroll
  for (int it = 0; it < 8; ++it) {
    int rowbase = wv * 16 + it * 2;
    const float4 v = *reinterpret_cast<const float4*>(
        flows + ((size_t)blk * 64 + rowbase) * 128 + lane * 4);
    int row = rowbase + r2;
    float ss = v.x * v.x + v.y * v.y + v.z * v.z + v.w * v.w;
    ss += __shfl_xor(ss, 16); ss += __shfl_xor(ss, 8);
    ss += __shfl_xor(ss, 4);  ss += __shfl_xor(ss, 2); ss += __shfl_xor(ss, 1);
    uint2 pk;
    pk.x = (unsigned)f2b(v.x) | ((unsigned)f2b(v.y) << 16);
    pk.y = (unsigned)f2b(v.z) | ((unsigned)f2b(v.w) << 16);
    *reinterpret_cast<uint2*>(A_ + row * 256 + ((c4 * 8) ^ ((row & 7) << 4))) = pk;
    if (c4 == 0) sArr[row] = rsqrtf(ss * (1.0f / 128.0f));
  }
}

template <int K, int N>
__device__ inline void sage_layer_nb(const char* Xsrc, char* Xdst,
                                     const float* sP, float* sN,
                                     const ushort* __restrict__ Wrp,
                                     const float* __restrict__ bias,
                                     int wv, int lr, int lg, int l64) {
  bf16x8 a[K / 32];
  float sr[4];
  int rowA = wv * 16 + lr;
  #pragma unroll
  for (int ks = 0; ks < K / 32; ++ks)
    a[ks] = *reinterpret_cast<const bf16x8*>(
        Xsrc + rowA * (K * 2) + ((ks * 64 + lg * 16) ^ ((rowA & 7) << 4)));
  #pragma unroll
  for (int rr = 0; rr < 4; ++rr) sr[rr] = sP[wv * 16 + 4 * lg + rr];
  float ssq[4] = {0.f, 0.f, 0.f, 0.f};
  #pragma unroll
  for (int nt = 0; nt < N / 16; ++nt) {
    int col = nt * 16 + lr;
    bf16x8 b[K / 32];
    #pragma unroll
    for (int ks = 0; ks < K / 32; ++ks)
      b[ks] = *reinterpret_cast<const bf16x8*>(Wrp + (((size_t)nt * (K / 32) + ks) * 64 + l64) * 8);
    f32x4 acc = {0.f, 0.f, 0.f, 0.f};
    #pragma unroll
    for (int ks = 0; ks < K / 32; ++ks)
      acc = __builtin_amdgcn_mfma_f32_16x16x32_bf16(a[ks], b[ks], acc, 0, 0, 0);
    float bb = bias[col];
    #pragma unroll
    for (int rr = 0; rr < 4; ++rr) {
      int row = wv * 16 + 4 * lg + rr;
      float y = acc[rr] * sr[rr] + bb;
      *reinterpret_cast<ushort*>(Xdst + row * (N * 2) + ((col * 2) ^ ((row & 7) << 4))) = f2b(y);
      ssq[rr] += y * y;
    }
  }
  #pragma unroll
  for (int rr = 0; rr < 4; ++rr) {
    float ss = ssq[rr];
    ss += __shfl_xor(ss, 1); ss += __shfl_xor(ss, 2);
    ss += __shfl_xor(ss, 4); ss += __shfl_xor(ss, 8);
    if (lr == 0) sN[wv * 16 + 4 * lg + rr] = 1.0f / fmaxf(sqrtf(ss), 1e-12f);
  }
}

__device__ inline void sage_layer_last_nb(const char* Xsrc, const float* sP,
                                          const ushort* __restrict__ Wrp,
                                          const float* __restrict__ bias,
                                          int wv, int lr, int lg, int l64,
                                          ushort* __restrict__ Fg, int blk) {
  bf16x8 a[4];
  float sr[4];
  int rowA = wv * 16 + lr;
  #pragma unroll
  for (int ks = 0; ks < 4; ++ks)
    a[ks] = *reinterpret_cast<const bf16x8*>(
        Xsrc + rowA * 256 + ((ks * 64 + lg * 16) ^ ((rowA & 7) << 4)));
  #pragma unroll
  for (int rr = 0; rr < 4; ++rr) sr[rr] = sP[wv * 16 + 4 * lg + rr];
  float yreg[8][4];
  float ssq[4] = {0.f, 0.f, 0.f, 0.f};
  #pragma unroll
  for (int nt = 0; nt < 8; ++nt) {
    int col = nt * 16 + lr;
    bf16x8 b[4];
    #pragma unroll
    for (int ks = 0; ks < 4; ++ks)
      b[ks] = *reinterpret_cast<const bf16x8*>(Wrp + (((size_t)nt * 4 + ks) * 64 + l64) * 8);
    f32x4 acc = {0.f, 0.f, 0.f, 0.f};
    #pragma unroll
    for (int ks = 0; ks < 4; ++ks)
      acc = __builtin_amdgcn_mfma_f32_16x16x32_bf16(a[ks], b[ks], acc, 0, 0, 0);
    float bb = bias[col];
    #pragma unroll
    for (int rr = 0; rr < 4; ++rr) {
      float y = acc[rr] * sr[rr] + bb;
      yreg[nt][rr] = y;
      float v = fmaxf(y, 0.f);
      ssq[rr] += v * v;
    }
  }
  float sc[4];
  #pragma unroll
  for (int rr = 0; rr < 4; ++rr) {
    float ss = ssq[rr];
    ss += __shfl_xor(ss, 1); ss += __shfl_xor(ss, 2);
    ss += __shfl_xor(ss, 4); ss += __shfl_xor(ss, 8);
    sc[rr] = sqrtf(128.0f / fmaxf(ss, 1e-20f));
  }
  #pragma unroll
  for (int nt = 0; nt < 8; ++nt)
    #pragma unroll
    for (int rr = 0; rr < 4; ++rr) {
      int row = wv * 16 + 4 * lg + rr;
      Fg[((size_t)blk * 64 + row) * 128 + nt * 16 + lr] = f2b(fmaxf(yreg[nt][rr], 0.f) * sc[rr]);
    }
}

// ---------------- mega2: chain (0..15) + prep_mb (16..23) + sage (24..533) ----------------
__global__ __launch_bounds__(256, 2) void mega2_k(
    const float* __restrict__ flows,
    const float* __restrict__ qsa, const float* __restrict__ ksa,
    const ushort* __restrict__ WL, const ushort* __restrict__ WR,
    const ushort* __restrict__ WRp,
    const float* __restrict__ bl1, const float* __restrict__ bl2,
    const float* __restrict__ bl3, const float* __restrict__ bl4,
    ushort* __restrict__ Fg, ushort* __restrict__ MBT,
    ushort* __restrict__ XT1, ushort* __restrict__ XT2, ushort* __restrict__ XT3,
    float* __restrict__ YT4, float* __restrict__ SS, unsigned* __restrict__ CTR) {
  __shared__ char L[74240];   // chain: XS 69632 | C0T 4096 | sArr 512 ; sage/prep_mb fit inside
  const int bid = blockIdx.x;
  const int tid = threadIdx.x;
  const int lane = tid & 63, wv = tid >> 6, lr = lane & 15, lg = lane >> 4;

  if (bid < 16) {
    // ---- chain path ----
    char* XS = L;
    char* C0T = L + 69632;
    float* sArr = (float*)(L + 73728);
    int cbid = bid;
    // L1: 8 blocks
    if (cbid < 8) {
      chain_dev<128, 128, 0>(XS, C0T, sArr, flows, nullptr, nullptr,
                             WL + 0, WR + 0, bl1, XT1, nullptr, SS + 0, cbid);
      ctr_signal(&CTR[0]);
    }
    ctr_wait(&CTR[0], 8);
    // L2: 16 blocks
    chain_dev<128, 256, 1>(XS, C0T, sArr, nullptr, XT1, SS + 0,
                           WL + 16384, WR + 16384, bl2, XT2, nullptr, SS + 128, cbid);
    ctr_signal(&CTR[1]);
    ctr_wait(&CTR[1], 16);
    // L3: 8 blocks
    if (cbid < 8) {
      chain_dev<256, 128, 1>(XS, C0T, sArr, nullptr, XT2, SS + 128,
                             WL + 49152, WR + 49152, bl3, XT3, nullptr, SS + 256, cbid);
      ctr_signal(&CTR[2]);
    }
    ctr_wait(&CTR[2], 8);
    // L4: 8 blocks
    if (cbid < 8) {
      chain_dev<128, 128, 2>(XS, C0T, sArr, nullptr, XT3, SS + 256,
                             WL + 81920, WR + 81920, bl4, nullptr, YT4, SS + 384, cbid);
      ctr_signal(&CTR[3]);
    }
    ctr_wait(&CTR[3], 8);
    // cl4b: 8 blocks x 256 threads cover 2048 items
    if (cbid < 8) {
      int t = cbid * 256 + tid;
      int r = t >> 4, cs = t & 15;
      float sc = sqrtf(128.0f / fmaxf(SS[384 + r], 1e-20f));
      ushort tmp[8];
      #pragma unroll
      for (int j = 0; j < 8; ++j) {
        int c = cs * 8 + j;
        tmp[j] = f2b(YT4[(size_t)c * 128 + r] * sc);
      }
      *reinterpret_cast<uint4*>(&Fg[(size_t)r * 128 + cs * 8]) = *reinterpret_cast<uint4*>(tmp);
    }
    return;
  }

  if (bid < 24) {
    // ---- prep_mb path ----
    char* QT  = L;
    char* KTm = L + 32768;
    int w = bid - 16;
    const float* qw = qsa + (size_t)w * 16384;
    const float* kw = ksa + (size_t)w * 16384;
    for (int e = tid; e < 16384; e += 256) {
      int op = e >> 7, c = e & 127;
      int off = c * 256 + ((op * 2) ^ ((c & 7) << 4));
      *reinterpret_cast<ushort*>(QT + off)  = f2b(qw[e]);
      *reinterpret_cast<ushort*>(KTm + off) = f2b(kw[e]);
    }
    __syncthreads();
    #pragma unroll
    for (int rt = 0; rt < 2; ++rt) {
      int e = wv * 32 + rt * 16 + lr;
      bf16x8 a[4];
      #pragma unroll
      for (int ks = 0; ks < 4; ++ks)
        a[ks] = *reinterpret_cast<const bf16x8*>(KTm + e * 256 + ((ks * 64 + lg * 16) ^ ((e & 7) << 4)));
      #pragma unroll
      for (int ct = 0; ct < 8; ++ct) {
        int d = ct * 16 + lr;
        bf16x8 bq[4];
        #pragma unroll
        for (int ks = 0; ks < 4; ++ks)
          bq[ks] = *reinterpret_cast<const bf16x8*>(QT + d * 256 + ((ks * 64 + lg * 16) ^ ((d & 7) << 4)));
        f32x4 acc = {0.f, 0.f, 0.f, 0.f};
        #pragma unroll
        for (int ks = 0; ks < 4; ++ks)
          acc = __builtin_amdgcn_mfma_f32_16x16x32_bf16(a[ks], bq[ks], acc, 0, 0, 0);
        uint2 pk;
        pk.x = (unsigned)f2b(acc[0]) | ((unsigned)f2b(acc[1]) << 16);
        pk.y = (unsigned)f2b(acc[2]) | ((unsigned)f2b(acc[3]) << 16);
        size_t base = ((((size_t)ct * 8 + w) * 4 + wv) * 64 +
                       (size_t)(((rt * 2 + (lg >> 1)) & 3) * 16 + lr)) * 8 + (lg & 1) * 4;
        *reinterpret_cast<uint2*>(&MBT[base]) = pk;
      }
    }
    return;
  }

  // ---- sage path ----
  char* A_ = L;
  char* B_ = L + 16384;
  char* C_ = L + 32768;
  float* sA = (float*)(L + 65536);
  float* sB = (float*)(L + 65792);
  const int l64 = lane;
  int blk = bid - 24 + 2;
  stage_flows_nb(flows, blk, A_, sA, wv, lane);
  asm volatile("" ::: "memory");
  sage_layer_nb<128, 128>(A_, B_, sA, sB, WRp + 0,     bl1, wv, lr, lg, l64);
  asm volatile("" ::: "memory");
  sage_layer_nb<128, 256>(B_, C_, sB, sA, WRp + 16384, bl2, wv, lr, lg, l64);
  asm volatile("" ::: "memory");
  sage_layer_nb<256, 128>(C_, A_, sA, sB, WRp + 49152, bl3, wv, lr, lg, l64);
  asm volatile("" ::: "memory");
  sage_layer_last_nb(A_, sB, WRp + 81920, bl4, wv, lr, lg, l64, Fg, blk);
}

// ---------------- attn v6: 512 blocks x 512 thr, dbuf RT, coalesced SBp/MBT ----------------
__global__ __launch_bounds__(512, 4) void attn_fused(
    const ushort* __restrict__ F, const ushort* __restrict__ MBT,
    const ushort* __restrict__ SBp, float* __restrict__ Out) {
  __shared__ char FT[32768];
  __shared__ char RTb[32768];

  const int bq = blockIdx.x;
  const int b = bq >> 1, ph = bq & 1;
  const int tid = threadIdx.x;
  const int l = tid & 63, wv = tid >> 6;
  const int lr = l & 15, lg = l >> 4;

  const ushort* Fb = F + (size_t)b * 16384;

  #pragma unroll
  for (int it = 0; it < 4; ++it) {
    int idx = tid + it * 512;
    int m = idx >> 4, eg = idx & 15;
    uint4 v = *reinterpret_cast<const uint4*>(Fb + m * 128 + eg * 8);
    const ushort* pv = reinterpret_cast<const ushort*>(&v);
    #pragma unroll
    for (int j = 0; j < 8; ++j) {
      int e = eg * 8 + j;
      *reinterpret_cast<ushort*>(FT + e * 256 + ((m * 2) ^ ftswz(e))) = pv[j];
    }
  }

  bf16x8 fa[4];
  {
    int n = wv * 16 + lr;
    #pragma unroll
    for (int ks = 0; ks < 4; ++ks)
      fa[ks] = *reinterpret_cast<const bf16x8*>(Fb + n * 128 + ks * 32 + lg * 8);
  }
  __syncthreads();

  bf16x8 af[4];
  {
    int e = wv * 16 + lr;
    #pragma unroll
    for (int ks = 0; ks < 4; ++ks)
      af[ks] = *reinterpret_cast<const bf16x8*>(
          FT + e * 256 + ((ks * 64 + lg * 16) ^ ftswz(e)));
  }

  f32x4 zacc[4];
  #pragma unroll
  for (int pt = 0; pt < 4; ++pt) zacc[pt] = f32x4{0.f, 0.f, 0.f, 0.f};

  const int eb0 = 2 * (wv * 16 + lg * 4);

  auto Rphase = [&](int w, char* RT) {
    #pragma unroll
    for (int pt = 0; pt < 4; ++pt) {
      int p = pt * 16 + lr;
      bf16x8 bs[4];
      #pragma unroll
      for (int ks = 0; ks < 4; ++ks)
        bs[ks] = *reinterpret_cast<const bf16x8*>(
            SBp + ((((size_t)(w * 2 + ph) * 4 + pt) * 4 + ks) * 64 + l) * 8);
      f32x4 rr = {0.f, 0.f, 0.f, 0.f};
      #pragma unroll
      for (int ks = 0; ks < 4; ++ks)
        rr = __builtin_amdgcn_mfma_f32_16x16x32_bf16(af[ks], bs[ks], rr, 0, 0, 0);
      uint2 pk;
      pk.x = (unsigned)f2b(rr[0]) | ((unsigned)f2b(rr[1]) << 16);
      pk.y = (unsigned)f2b(rr[2]) | ((unsigned)f2b(rr[3]) << 16);
      *reinterpret_cast<uint2*>(RT + p * 256 + (eb0 ^ ((p & 7) << 4))) = pk;
    }
  };
  auto Zphase = [&](int w, const char* RT) {
    bf16x8 mf[4];
    #pragma unroll
    for (int ks = 0; ks < 4; ++ks)
      mf[ks] = *reinterpret_cast<const bf16x8*>(
          MBT + ((((size_t)wv * 8 + w) * 4 + ks) * 64 + l) * 8);
    #pragma unroll
    for (int pt = 0; pt < 4; ++pt) {
      int p = pt * 16 + lr;
      bf16x8 bg[4];
      #pragma unroll
      for (int ks = 0; ks < 4; ++ks)
        bg[ks] = *reinterpret_cast<const bf16x8*>(
            RT + p * 256 + ((ks * 64 + lg * 16) ^ ((p & 7) << 4)));
      #pragma unroll
      for (int ks = 0; ks < 4; ++ks)
        zacc[pt] = __builtin_amdgcn_mfma_f32_16x16x32_bf16(mf[ks], bg[ks], zacc[pt], 0, 0, 0);
    }
  };

  Rphase(0, RTb);
  __syncthreads();
  #pragma unroll
  for (int w = 0; w < 7; ++w) {
    Zphase(w, RTb + (w & 1) * 16384);
    Rphase(w + 1, RTb + ((w + 1) & 1) * 16384);
    __syncthreads();
  }
  Zphase(7, RTb + 16384);
  #pragma unroll
  for (int pt = 0; pt < 4; ++pt) {
    int p = pt * 16 + lr;
    uint2 pk;
    pk.x = (unsigned)f2b(zacc[pt][0]) | ((unsigned)f2b(zacc[pt][1]) << 16);
    pk.y = (unsigned)f2b(zacc[pt][2]) | ((unsigned)f2b(zacc[pt][3]) << 16);
    *reinterpret_cast<uint2*>(RTb + p * 256 + (eb0 ^ ((p & 7) << 4))) = pk;
  }
  __syncthreads();

  const float inv_scale = 0.08838834764831845f;
  float* ob = Out + (size_t)b * 16384 + ph * 64;
  #pragma unroll
  for (int pt = 0; pt < 4; ++pt) {
    int p = pt * 16 + lr;
    bf16x8 bz[4];
    #pragma unroll
    for (int ks = 0; ks < 4; ++ks)
      bz[ks] = *reinterpret_cast<const bf16x8*>(
          RTb + p * 256 + ((ks * 64 + lg * 16) ^ ((p & 7) << 4)));
    f32x4 oa = {0.f, 0.f, 0.f, 0.f};
    #pragma unroll
    for (int ks = 0; ks < 4; ++ks)
      oa = __builtin_amdgcn_mfma_f32_16x16x32_bf16(fa[ks], bz[ks], oa, 0, 0, 0);
    int n0 = wv * 16 + lg * 4;
    #pragma unroll
    for (int r = 0; r < 4; ++r)
      ob[(size_t)(n0 + r) * 128 + p] = oa[r] * inv_scale;
  }
}

extern "C" void kernel_launch(void* const* d_in, const int* in_sizes, int n_in,
                              void* d_out, int out_size, void* d_ws, size_t ws_size,
                              hipStream_t stream) {
  const float* flows = (const float*)d_in[0];
  const float* g1_wl = (const float*)d_in[10];
  const float* g1_bl = (const float*)d_in[11];
  const float* g1_wr = (const float*)d_in[12];
  const float* g2_wl = (const float*)d_in[13];
  const float* g2_bl = (const float*)d_in[14];
  const float* g2_wr = (const float*)d_in[15];
  const float* g3_wl = (const float*)d_in[16];
  const float* g3_bl = (const float*)d_in[17];
  const float* g3_wr = (const float*)d_in[18];
  const float* g4_wl = (const float*)d_in[19];
  const float* g4_bl = (const float*)d_in[20];
  const float* g4_wr = (const float*)d_in[21];
  const float* qsa   = (const float*)d_in[24];
  const float* ksa   = (const float*)d_in[25];
  const float* s2w   = (const float*)d_in[27];
  float* out = (float*)d_out;
  char* wsb  = (char*)d_ws;

  // workspace layout (bytes)
  ushort* FB16 = (ushort*)(wsb);                 // 32768*128 bf16 = 8388608
  ushort* SBp  = (ushort*)(wsb + 8388608);       // 131072 bf16 (permuted)
  ushort* WL   = (ushort*)(wsb + 8650752);       // 98304 bf16
  ushort* WR   = (ushort*)(wsb + 8847360);       // 98304 bf16
  ushort* MBT  = (ushort*)(wsb + 9043968);       // 131072 bf16 (permuted)
  ushort* XT1  = (ushort*)(wsb + 9306112);       // 128*128 bf16
  ushort* XT2  = (ushort*)(wsb + 9338880);       // 256*128 bf16
  ushort* XT3  = (ushort*)(wsb + 9404416);       // 128*128 bf16
  float*  YT4  = (float*)(wsb + 9437184);        // 128*128 f32
  float*  SS   = (float*)(wsb + 9502720);        // 512 f32
  ushort* WRp  = (ushort*)(wsb + 9504768);       // 98304 bf16 (permuted)
  unsigned* CTR = (unsigned*)(wsb + 9701376);    // 8 u32 chain layer counters

  prep_all_k<<<896, 256, 0, stream>>>(s2w,
                                      g1_wl, g2_wl, g3_wl, g4_wl,
                                      g1_wr, g2_wr, g3_wr, g4_wr,
                                      SBp, WL, WR, WRp, SS, CTR);
  mega2_k<<<534, 256, 0, stream>>>(flows, qsa, ksa, WL, WR, WRp,
                                   g1_bl, g2_bl, g3_bl, g4_bl,
                                   FB16, MBT, XT1, XT2, XT3, YT4, SS, CTR);
  attn_fused<<<512, 512, 0, stream>>>(FB16, MBT, SBp, out);
}